// Round 24
// baseline (543.801 us; speedup 1.0000x reference)
//
#include <hip/hip_runtime.h>
#include <cstddef>
#include <cstdint>

#define DEV __device__ __forceinline__

namespace {

constexpr int kH = 8;
constexpr int kB = 32, kT = 1024, kNT = 77, kR = 4, kLR = 256;
constexpr int kRL = kR * kLR;            // 1024
constexpr float kNEG = -1000000.0f;
constexpr int kNtot = 2304;              // padded n per (b,h,d) row (3*768)
constexpr int kNS2 = 3;                  // attention slices of 768 n

typedef __bf16 bf16x8 __attribute__((ext_vector_type(8)));
typedef float f32x4 __attribute__((ext_vector_type(4)));

DEV unsigned short f2bf(float f) {
  unsigned int u = __float_as_uint(f);
  u += 0x7fffu + ((u >> 16) & 1u);
  return (unsigned short)(u >> 16);
}
DEV float bf2f(unsigned short h) { return __uint_as_float(((unsigned int)h) << 16); }

DEV float wave_sum(float v) {
  #pragma unroll
  for (int s = 32; s; s >>= 1) v += __shfl_xor(v, s);
  return v;
}

// XCD-aware bijective swizzle (T1): contiguous grid chunk per XCD.
DEV int xcd_swz(int bid, int nwg) {
  if ((nwg & 7) == 0) return (bid & 7) * (nwg >> 3) + (bid >> 3);
  return bid;
}

// ---------------- LayerNorm -> bf16 ----------------
template<int COLS>
__global__ __launch_bounds__(256) void ln_bf16(const float* __restrict__ in,
    const float* __restrict__ g, const float* __restrict__ be,
    unsigned short* __restrict__ out) {
  constexpr int PT = COLS / 256;
  int row = blockIdx.x;
  const float* p = in + (size_t)row * COLS;
  unsigned short* o = out + (size_t)row * COLS;
  float v[PT]; float s = 0.f, s2 = 0.f;
  #pragma unroll
  for (int i = 0; i < PT; i++) {
    v[i] = p[threadIdx.x + i * 256];
    s += v[i]; s2 += v[i] * v[i];
  }
  __shared__ float red[2][4];
  int lane = threadIdx.x & 63, w = threadIdx.x >> 6;
  s = wave_sum(s); s2 = wave_sum(s2);
  if (!lane) { red[0][w] = s; red[1][w] = s2; }
  __syncthreads();
  s = red[0][0] + red[0][1] + red[0][2] + red[0][3];
  s2 = red[1][0] + red[1][1] + red[1][2] + red[1][3];
  float mean = s / COLS;
  float var = s2 / COLS - mean * mean;
  float rstd = rsqrtf(var + 1e-5f);
  #pragma unroll
  for (int i = 0; i < PT; i++) {
    int c = threadIdx.x + i * 256;
    o[c] = f2bf((v[i] - mean) * rstd * g[c] + be[c]);
  }
}

// ---- retrieval stats: mean/rstd scalars + motion cast ----
__global__ __launch_bounds__(256) void rfk_stats(const float* __restrict__ mot,
    const float* __restrict__ txt, unsigned short* __restrict__ mot_bf,
    float* __restrict__ s1k, float* __restrict__ s2k,
    float* __restrict__ s1v, float* __restrict__ s2v) {
  int m = blockIdx.x;
  const float* pm = mot + (size_t)m * 512;
  const float* pt = txt + (size_t)(m >> 8) * 512;
  float v[2], t[2];
  float sv = 0.f, sv2 = 0.f, st = 0.f, st2 = 0.f;
  #pragma unroll
  for (int i = 0; i < 2; i++) {
    v[i] = pm[threadIdx.x + i * 256]; sv += v[i]; sv2 += v[i] * v[i];
    t[i] = pt[threadIdx.x + i * 256]; st += t[i]; st2 += t[i] * t[i];
  }
  __shared__ float red[4][4];
  int lane = threadIdx.x & 63, w = threadIdx.x >> 6;
  sv = wave_sum(sv); sv2 = wave_sum(sv2); st = wave_sum(st); st2 = wave_sum(st2);
  if (!lane) { red[0][w] = sv; red[1][w] = sv2; red[2][w] = st; red[3][w] = st2; }
  __syncthreads();
  #pragma unroll
  for (int i = 0; i < 2; i++)
    mot_bf[(size_t)m * 512 + threadIdx.x + i * 256] = f2bf(v[i]);
  if (threadIdx.x == 0) {
    float SV = red[0][0] + red[0][1] + red[0][2] + red[0][3];
    float SV2 = red[1][0] + red[1][1] + red[1][2] + red[1][3];
    float ST = red[2][0] + red[2][1] + red[2][2] + red[2][3];
    float ST2 = red[3][0] + red[3][1] + red[3][2] + red[3][3];
    float SA = SV + ST, SA2 = SV2 + ST2;
    float ma = SA / 1024.f, va = SA2 / 1024.f - ma * ma;
    float ra = rsqrtf(va + 1e-5f);
    float mv = SV / 512.f, vv = SV2 / 512.f - mv * mv;
    float rv = rsqrtf(vv + 1e-5f);
    s1k[m] = ra; s2k[m] = -ra * ma;
    s1v[m] = rv; s2v[m] = -rv * mv;
  }
}

// ---- fold LN gains into retrieval weights (into wcat1 halves); per-col constants ----
__global__ __launch_bounds__(256) void prep_w(
    const float* __restrict__ Wkr, const float* __restrict__ g1,
    const float* __restrict__ b1, const float* __restrict__ bkr,
    const float* __restrict__ Wvr, const float* __restrict__ g2,
    const float* __restrict__ b2, const float* __restrict__ bvr,
    unsigned short* __restrict__ w1lo, unsigned short* __restrict__ w2,
    float* __restrict__ G1, float* __restrict__ B1,
    float* __restrict__ G2, float* __restrict__ B2) {
  int n = blockIdx.x;   // 512
  int tid = threadIdx.x;
  float gs = 0.f, bs = 0.f;
  #pragma unroll
  for (int i = 0; i < 4; i++) {
    int k = tid + i * 256;
    float w = Wkr[(size_t)n * 1024 + k];
    float gv = g1[k];
    gs += gv * w; bs += b1[k] * w;
    if (i < 2) w1lo[(size_t)n * 512 + k] = f2bf(gv * w);
  }
  float g2s = 0.f, b2s = 0.f;
  #pragma unroll
  for (int i = 0; i < 2; i++) {
    int k = tid + i * 256;
    float w = Wvr[(size_t)n * 512 + k];
    g2s += g2[k] * w; b2s += b2[k] * w;
    w2[(size_t)n * 512 + k] = f2bf(g2[k] * w);
  }
  __shared__ float red[4][4];
  int lane = tid & 63, w_ = tid >> 6;
  gs = wave_sum(gs); bs = wave_sum(bs); g2s = wave_sum(g2s); b2s = wave_sum(b2s);
  if (!lane) { red[0][w_] = gs; red[1][w_] = bs; red[2][w_] = g2s; red[3][w_] = b2s; }
  __syncthreads();
  if (tid == 0) {
    G1[n] = red[0][0] + red[0][1] + red[0][2] + red[0][3];
    B1[n] = red[1][0] + red[1][1] + red[1][2] + red[1][3] + bkr[n];
    G2[n] = red[2][0] + red[2][1] + red[2][2] + red[2][3];
    B2[n] = red[3][0] + red[3][1] + red[3][2] + red[3][3] + bvr[n];
  }
}

// ---- T[m][n] = (g1_hi * text[m]) . Wkr[n, 512:1024] ; grid (128 m, 8 n-slices) ----
__global__ __launch_bounds__(256) void text_T(const float* __restrict__ re_text,
    const float* __restrict__ g1, const float* __restrict__ Wkr,
    float* __restrict__ T) {
  int m = blockIdx.x;
  int ns = blockIdx.y;
  __shared__ float tr[512];
  int tid = threadIdx.x;
  #pragma unroll
  for (int i = 0; i < 2; i++) {
    int k = tid + i * 256;
    tr[k] = re_text[(size_t)m * 512 + k] * g1[512 + k];
  }
  __syncthreads();
  int n = ns * 64 + (tid >> 2);
  int k0 = (tid & 3) * 128;
  const float* wp = Wkr + (size_t)n * 1024 + 512 + k0;
  float acc = 0.f;
  #pragma unroll
  for (int k = 0; k < 128; k += 4) {
    float4 w4 = *reinterpret_cast<const float4*>(wp + k);
    float4 t4 = *reinterpret_cast<const float4*>(&tr[k0 + k]);
    acc = fmaf(t4.x, w4.x, fmaf(t4.y, w4.y, fmaf(t4.z, w4.z, fmaf(t4.w, w4.w, acc))));
  }
  acc += __shfl_xor(acc, 1);
  acc += __shfl_xor(acc, 2);
  if ((tid & 3) == 0) T[(size_t)m * 512 + n] = acc;
}

// ---------------- per-row mask arrays (full batch) ----------------
__global__ __launch_bounds__(256) void rowmask_kernel(const int* __restrict__ ct,
    const float* __restrict__ src_mask, const float* __restrict__ re_mask,
    float* __restrict__ kaT, float* __restrict__ kaR, float* __restrict__ kaM,
    float* __restrict__ vmT, float* __restrict__ vmR, float* __restrict__ vmM,
    int nB) {
  int i = blockIdx.x * 256 + threadIdx.x;
  if (i < nB * kRL) {
    int b = i >> 10;
    int c = ct[b];
    float retr = (c / 10 > 0) ? 1.f : 0.f;
    float rm = re_mask[i];
    kaR[i] = (1.f - retr) * kNEG + (1.f - rm) * kNEG;
    vmR[i] = retr * rm;
    float sm = src_mask[i];
    kaM[i] = (1.f - sm) * kNEG;
    vmM[i] = sm;
  }
  if (i < nB * kNT) {
    int b = i / kNT;
    int c = ct[b];
    float text = (c % 10 > 0) ? 1.f : 0.f;
    kaT[i] = (1.f - text) * kNEG;
    vmT[i] = text;
  }
}

// ---------------- weight cast f32 -> bf16 ----------------
__global__ __launch_bounds__(256) void castw(const float* __restrict__ s,
    unsigned short* __restrict__ d, int n) {
  int i = (blockIdx.x * 256 + threadIdx.x) * 4;
  if (i < n) {
    float4 v = *reinterpret_cast<const float4*>(s + i);
    ushort4 o;
    o.x = f2bf(v.x); o.y = f2bf(v.y); o.z = f2bf(v.z); o.w = f2bf(v.w);
    *reinterpret_cast<ushort4*>(d + i) = o;
  }
}

// ---------------- zero-pad tail of E'/V' rows ----------------
__global__ __launch_bounds__(256) void zpad_kernel(unsigned short* __restrict__ E,
    unsigned short* __restrict__ V, int rows) {
  int i = blockIdx.x * 256 + threadIdx.x;
  if (i >= rows * 24) return;
  int row = i / 24, c = i % 24;
  size_t off = (size_t)row * kNtot + 2112 + c * 8;
  ulonglong2 z; z.x = 0; z.y = 0;
  *reinterpret_cast<ulonglong2*>(E + off) = z;
  *reinterpret_cast<ulonglong2*>(V + off) = z;
}

// ---------------- silu(emb) precompute (f32) ----------------
__global__ __launch_bounds__(256) void silu_emb(const float* __restrict__ emb,
    float* __restrict__ semb) {
  int i = (blockIdx.x * 256 + threadIdx.x) * 4;
  float4 v = *reinterpret_cast<const float4*>(emb + i);
  float4 o;
  o.x = v.x / (1.f + __expf(-v.x));
  o.y = v.y / (1.f + __expf(-v.y));
  o.z = v.z / (1.f + __expf(-v.z));
  o.w = v.w / (1.f + __expf(-v.w));
  *reinterpret_cast<float4*>(semb + i) = o;
}

// ---------------- emb GEMV split-K ----------------
__global__ __launch_bounds__(256) void emb_gemv2(const float* __restrict__ semb,
    const float* __restrict__ W, float* __restrict__ part) {
  int n = blockIdx.x * 4 + (threadIdx.x >> 6);
  int s = blockIdx.y;
  int lane = threadIdx.x & 63;
  int k = s * 256 + lane * 4;
  float4 wv = *reinterpret_cast<const float4*>(&W[(size_t)n * 2048 + k]);
  float acc[32];
  #pragma unroll
  for (int m = 0; m < 32; m++) {
    float4 sv = *reinterpret_cast<const float4*>(&semb[(size_t)m * 2048 + k]);
    acc[m] = fmaf(sv.x, wv.x, fmaf(sv.y, wv.y, fmaf(sv.z, wv.z, sv.w * wv.w)));
  }
  #pragma unroll
  for (int m = 0; m < 32; m++) {
    float t = wave_sum(acc[m]);
    if (lane == 0) part[((size_t)s * 32 + m) * 1024 + n] = t;
  }
}
__global__ __launch_bounds__(256) void emb_fin(const float* __restrict__ part,
    const float* __restrict__ bias, float* __restrict__ ss) {
  int i = blockIdx.x * 256 + threadIdx.x;
  float s = 0.f;
  #pragma unroll
  for (int c = 0; c < 8; c++) s += part[(size_t)c * 32768 + i];
  ss[i] = s + bias[i & 1023];
}

// ================= MERGED FUSED MFMA GEMM (3 combos, one launch) =================
// 3-buffer pipelined K-loop with counted vmcnt; raw barriers (no drain).
// Block-range dispatch: [0,G0)=combo0, [G0,G0+G1)=combo1, rest=combo2.
// Per-range bijective XCD swizzle.
__global__ __launch_bounds__(256) void gemm_fused_all(
    int nG0, int nG1,
    const unsigned short* __restrict__ A0, const unsigned short* __restrict__ A1,
    const unsigned short* __restrict__ A2,
    const unsigned short* __restrict__ W0, const unsigned short* __restrict__ W1,
    const unsigned short* __restrict__ W2,
    int M0, int M2,
    unsigned short* __restrict__ qout, unsigned short* __restrict__ E,
    unsigned short* __restrict__ V,
    const float* __restrict__ bq, const float* __restrict__ bkm,
    const float* __restrict__ bvm,
    const float* __restrict__ B1v, const float* __restrict__ B2v,
    const float* __restrict__ bkt, const float* __restrict__ bvt,
    const float* __restrict__ kaM, const float* __restrict__ vmM,
    const float* __restrict__ kaR, const float* __restrict__ vmR,
    const float* __restrict__ kaT, const float* __restrict__ vmT,
    const float* __restrict__ s1k, const float* __restrict__ s2k,
    const float* __restrict__ s1v, const float* __restrict__ s2v,
    const float* __restrict__ G1v, const float* __restrict__ G2v,
    const float* __restrict__ Tt) {
  __shared__ __align__(16) char smem[49152];   // 3x16KB staging | 32KB epilogue
  unsigned short* lds = (unsigned short*)smem;
  const int tid = threadIdx.x;
  const int lane = tid & 63;
  const int wv = tid >> 6;
  const int wr = (wv >> 1) * 64;
  const int wc = (wv & 1) * 64;

  int bid = blockIdx.x;
  int combo, wg, NX, K, M, m_per_b, out_off;
  const unsigned short *A, *W;
  if (bid < nG0) {
    combo = 0; wg = xcd_swz(bid, nG0); NX = 12; K = 512; M = M0;
    m_per_b = kT; out_off = kNT + kRL; A = A0; W = W0;
  } else if (bid < nG0 + nG1) {
    combo = 1; wg = xcd_swz(bid - nG0, nG1); NX = 8; K = 512; M = M0;
    m_per_b = kRL; out_off = kNT; A = A1; W = W1;
  } else {
    int nG2 = (int)gridDim.x - nG0 - nG1;
    combo = 2; wg = xcd_swz(bid - nG0 - nG1, nG2); NX = 8; K = 256; M = M2;
    m_per_b = kNT; out_off = 0; A = A2; W = W2;
  }
  const int m0 = (wg / NX) * 128;
  const int n0 = (wg % NX) * 128;
  const int sec = n0 >> 9;
  const int nlo = n0 & 511;

  const unsigned short* srcA[2]; const unsigned short* srcB[2];
  int dstOff[2];
  #pragma unroll
  for (int i = 0; i < 2; i++) {
    int lin = i * 256 + tid;
    int r = lin >> 2, cl = lin & 3;
    int cs = cl ^ ((r >> 1) & 3);
    int ra = m0 + r; if (ra > M - 1) ra = M - 1;
    srcA[i] = A + (size_t)ra * K + cs * 8;
    srcB[i] = W + (size_t)(n0 + r) * K + cs * 8;
    dstOff[i] = lin * 8;
  }
  int offA[4], offB[4];
  #pragma unroll
  for (int i = 0; i < 4; i++) {
    int r = wr + i * 16 + (lane & 15);
    int c = (lane >> 4) ^ ((r >> 1) & 3);
    offA[i] = r * 32 + c * 8;
    int rb = wc + i * 16 + (lane & 15);
    int cb = (lane >> 4) ^ ((rb >> 1) & 3);
    offB[i] = rb * 32 + cb * 8;
  }

  f32x4 acc[4][4] = {};
  const int nt = K >> 5;

  #pragma unroll
  for (int i = 0; i < 2; i++) {
    __builtin_amdgcn_global_load_lds(
        (const __attribute__((address_space(1))) void*)(srcA[i]),
        (__attribute__((address_space(3))) void*)&lds[dstOff[i]], 16, 0, 0);
    __builtin_amdgcn_global_load_lds(
        (const __attribute__((address_space(1))) void*)(srcB[i]),
        (__attribute__((address_space(3))) void*)&lds[4096 + dstOff[i]], 16, 0, 0);
  }

  int cur = 0;
  for (int t = 0; t < nt; t++) {
    int nxt = cur + 1; if (nxt == 3) nxt = 0;
    if (t + 1 < nt) {
      int ko = (t + 1) << 5;
      #pragma unroll
      for (int i = 0; i < 2; i++) {
        __builtin_amdgcn_global_load_lds(
            (const __attribute__((address_space(1))) void*)(srcA[i] + ko),
            (__attribute__((address_space(3))) void*)&lds[nxt * 8192 + dstOff[i]], 16, 0, 0);
        __builtin_amdgcn_global_load_lds(
            (const __attribute__((address_space(1))) void*)(srcB[i] + ko),
            (__attribute__((address_space(3))) void*)&lds[nxt * 8192 + 4096 + dstOff[i]], 16, 0, 0);
      }
      asm volatile("s_waitcnt vmcnt(4)" ::: "memory");
    } else {
      asm volatile("s_waitcnt vmcnt(0)" ::: "memory");
    }
    __builtin_amdgcn_s_barrier();
    __builtin_amdgcn_sched_barrier(0);
    bf16x8 af[4], bf[4];
    #pragma unroll
    for (int i = 0; i < 4; i++) {
      af[i] = *reinterpret_cast<const bf16x8*>(&lds[cur * 8192 + offA[i]]);
      bf[i] = *reinterpret_cast<const bf16x8*>(&lds[cur * 8192 + 4096 + offB[i]]);
    }
    #pragma unroll
    for (int i = 0; i < 4; i++)
      #pragma unroll
      for (int j = 0; j < 4; j++)
        acc[i][j] = __builtin_amdgcn_mfma_f32_16x16x32_bf16(af[i], bf[j], acc[i][j], 0, 0, 0);
    cur = nxt;
  }
  __syncthreads();   // all loads done; sync before epilogue reuses LDS

  const int r4 = (lane >> 4) << 2;
  const int rowb = m0 + wr + r4;

  auto epival = [&](float accv, int rowg, int cl) -> float {
    if (combo == 0) {
      if (sec == 0) return __expf(accv + bq[cl]);
      if (sec == 1) return __expf(accv + bkm[cl] + kaM[rowg]);
      return (accv + bvm[cl]) * vmM[rowg];
    } else if (combo == 1) {
      if (sec == 0)
        return __expf((accv + Tt[(size_t)(rowg >> 8) * 512 + cl]) * s1k[rowg]
                      + s2k[rowg] * G1v[cl] + B1v[cl] + kaR[rowg]);
      return (accv * s1v[rowg] + s2v[rowg] * G2v[cl] + B2v[cl]) * vmR[rowg];
    } else {
      if (sec == 0) return __expf(accv + bkt[cl] + kaT[rowg]);
      return (accv + bvt[cl]) * vmT[rowg];
    }
  };

  unsigned short* dstEV = (combo == 0) ? (sec == 1 ? E : V) : (sec == 0 ? E : V);

  if (combo == 2) {
    // scalar transposed epilogue (m_per_b = 77)
    #pragma unroll
    for (int i = 0; i < 4; i++) {
      #pragma unroll
      for (int r = 0; r < 4; r++) {
        int row = rowb + i * 16 + r;
        if (row >= M) continue;
        size_t nn = out_off + (row % m_per_b);
        size_t cb = (size_t)(row / m_per_b) * 512;
        #pragma unroll
        for (int j = 0; j < 4; j++) {
          int cl = nlo + wc + j * 16 + (lane & 15);
          dstEV[(cb + cl) * kNtot + nn] = f2bf(epival(acc[i][j][r], row, cl));
        }
      }
    }
    return;
  }

  // staged epilogue [128][128] bf16, XOR-keyed
  unsigned short* S = (unsigned short*)smem;
  #pragma unroll
  for (int i = 0; i < 4; i++) {
    #pragma unroll
    for (int r = 0; r < 4; r++) {
      int row_t = wr + i * 16 + r4 + r;
      int rowg = m0 + row_t; if (rowg > M - 1) rowg = M - 1;
      int key = ((row_t >> 3) & 7) << 3;
      #pragma unroll
      for (int j = 0; j < 4; j++) {
        int col_t = wc + j * 16 + (lane & 15);
        S[row_t * 128 + (col_t ^ key)] = f2bf(epival(acc[i][j][r], rowg, nlo + col_t));
      }
    }
  }
  __syncthreads();
  bool linear = (combo == 0 && sec == 0);
  if (linear) {
    #pragma unroll
    for (int it = 0; it < 8; it++) {
      int slot = it * 256 + tid;
      int row_t = slot >> 4;
      int cs = (slot & 15) * 8;
      int key = ((row_t >> 3) & 7) << 3;
      int row = m0 + row_t;
      if (row < M) {
        ulonglong2 d = *reinterpret_cast<const ulonglong2*>(&S[row_t * 128 + (cs ^ key)]);
        *reinterpret_cast<ulonglong2*>(qout + (size_t)row * 512 + nlo + cs) = d;
      }
    }
  } else {
    #pragma unroll
    for (int it = 0; it < 8; it++) {
      int slot = it * 256 + tid;
      int col_t = slot >> 4;
      int mcx = slot & 15;
      int mc = mcx * 8;
      int key = (mcx & 7) << 3;
      union { unsigned short u[8]; ulonglong2 v; } w;
      #pragma unroll
      for (int e = 0; e < 8; e++)
        w.u[e] = S[(mc + e) * 128 + (col_t ^ key)];
      int row = m0 + mc;   // M % 128 == 0 here
      size_t obase = ((size_t)(row / m_per_b) * 512 + nlo + col_t) * (size_t)kNtot
                   + out_off + (row % m_per_b);
      *reinterpret_cast<ulonglong2*>(dstEV + obase) = w.v;
    }
  }
}

// ------- plain MFMA GEMM (final projection) + fused residual: out = x + (C+bias) -------
__global__ __launch_bounds__(256) void gemm_mfma(
    const unsigned short* __restrict__ A, const unsigned short* __restrict__ W,
    const float* __restrict__ bias, const float* __restrict__ Xres,
    float* __restrict__ Outf, int M, int K) {
  __shared__ __align__(16) char smem[49152];
  unsigned short* lds = (unsigned short*)smem;
  const int tid = threadIdx.x;
  const int lane = tid & 63;
  const int wv = tid >> 6;
  const int wr = (wv >> 1) * 64;
  const int wc = (wv & 1) * 64;
  const int wg = xcd_swz(blockIdx.x, gridDim.x);
  const int m0 = (wg >> 2) * 128;
  const int n0 = (wg & 3) * 128;

  const unsigned short* srcA[2]; const unsigned short* srcB[2];
  int dstOff[2];
  #pragma unroll
  for (int i = 0; i < 2; i++) {
    int lin = i * 256 + tid;
    int r = lin >> 2, cl = lin & 3;
    int cs = cl ^ ((r >> 1) & 3);
    int ra = m0 + r; if (ra > M - 1) ra = M - 1;
    srcA[i] = A + (size_t)ra * K + cs * 8;
    srcB[i] = W + (size_t)(n0 + r) * K + cs * 8;
    dstOff[i] = lin * 8;
  }
  int offA[4], offB[4];
  #pragma unroll
  for (int i = 0; i < 4; i++) {
    int r = wr + i * 16 + (lane & 15);
    int c = (lane >> 4) ^ ((r >> 1) & 3);
    offA[i] = r * 32 + c * 8;
    int rb = wc + i * 16 + (lane & 15);
    int cb = (lane >> 4) ^ ((rb >> 1) & 3);
    offB[i] = rb * 32 + cb * 8;
  }

  f32x4 acc[4][4] = {};
  const int nt = K >> 5;

  #pragma unroll
  for (int i = 0; i < 2; i++) {
    __builtin_amdgcn_global_load_lds(
        (const __attribute__((address_space(1))) void*)(srcA[i]),
        (__attribute__((address_space(3))) void*)&lds[dstOff[i]], 16, 0, 0);
    __builtin_amdgcn_global_load_lds(
        (const __attribute__((address_space(1))) void*)(srcB[i]),
        (__attribute__((address_space(3))) void*)&lds[4096 + dstOff[i]], 16, 0, 0);
  }

  int cur = 0;
  for (int t = 0; t < nt; t++) {
    int nxt = cur + 1; if (nxt == 3) nxt = 0;
    if (t + 1 < nt) {
      int ko = (t + 1) << 5;
      #pragma unroll
      for (int i = 0; i < 2; i++) {
        __builtin_amdgcn_global_load_lds(
            (const __attribute__((address_space(1))) void*)(srcA[i] + ko),
            (__attribute__((address_space(3))) void*)&lds[nxt * 8192 + dstOff[i]], 16, 0, 0);
        __builtin_amdgcn_global_load_lds(
            (const __attribute__((address_space(1))) void*)(srcB[i] + ko),
            (__attribute__((address_space(3))) void*)&lds[nxt * 8192 + 4096 + dstOff[i]], 16, 0, 0);
      }
      asm volatile("s_waitcnt vmcnt(4)" ::: "memory");
    } else {
      asm volatile("s_waitcnt vmcnt(0)" ::: "memory");
    }
    __builtin_amdgcn_s_barrier();
    __builtin_amdgcn_sched_barrier(0);
    bf16x8 af[4], bf[4];
    #pragma unroll
    for (int i = 0; i < 4; i++) {
      af[i] = *reinterpret_cast<const bf16x8*>(&lds[cur * 8192 + offA[i]]);
      bf[i] = *reinterpret_cast<const bf16x8*>(&lds[cur * 8192 + 4096 + offB[i]]);
    }
    #pragma unroll
    for (int i = 0; i < 4; i++)
      #pragma unroll
      for (int j = 0; j < 4; j++)
        acc[i][j] = __builtin_amdgcn_mfma_f32_16x16x32_bf16(af[i], bf[j], acc[i][j], 0, 0, 0);
    cur = nxt;
  }
  __syncthreads();

  const int r4 = (lane >> 4) << 2;
  unsigned short* S = (unsigned short*)smem;
  #pragma unroll
  for (int i = 0; i < 4; i++) {
    #pragma unroll
    for (int r = 0; r < 4; r++) {
      int row_t = wr + i * 16 + r4 + r;
      int key = ((row_t >> 3) & 7) << 3;
      #pragma unroll
      for (int j = 0; j < 4; j++) {
        int col_t = wc + j * 16 + (lane & 15);
        S[row_t * 128 + (col_t ^ key)] = f2bf(acc[i][j][r] + bias[n0 + col_t]);
      }
    }
  }
  __syncthreads();
  #pragma unroll
  for (int it = 0; it < 8; it++) {
    int slot = it * 256 + tid;
    int row_t = slot >> 4;
    int cs = (slot & 15) * 8;
    int key = ((row_t >> 3) & 7) << 3;
    int row = m0 + row_t;
    if (row < M) {
      union { unsigned short u[8]; ulonglong2 v; } w;
      w.v = *reinterpret_cast<const ulonglong2*>(&S[row_t * 128 + (cs ^ key)]);
      const float* xp = Xres + (size_t)row * 512 + n0 + cs;
      float4 x0 = *reinterpret_cast<const float4*>(xp);
      float4 x1 = *reinterpret_cast<const float4*>(xp + 4);
      float4 o0, o1;
      o0.x = x0.x + bf2f(w.u[0]); o0.y = x0.y + bf2f(w.u[1]);
      o0.z = x0.z + bf2f(w.u[2]); o0.w = x0.w + bf2f(w.u[3]);
      o1.x = x1.x + bf2f(w.u[4]); o1.y = x1.y + bf2f(w.u[5]);
      o1.z = x1.z + bf2f(w.u[6]); o1.w = x1.w + bf2f(w.u[7]);
      float* op = Outf + (size_t)row * 512 + n0 + cs;
      *reinterpret_cast<float4*>(op) = o0;
      *reinterpret_cast<float4*>(op + 4) = o1;
    }
  }
}

// ---- attention partials via MFMA (NT form), wave-per-d-slab ----
__global__ __launch_bounds__(256) void attp_kernel(const unsigned short* __restrict__ E,
    const unsigned short* __restrict__ V, float* __restrict__ part,
    float* __restrict__ part_cs) {
  int bh = blockIdx.x;
  int s = blockIdx.y;
  const unsigned short* Ep = E + (size_t)bh * 64 * kNtot;
  const unsigned short* Vp = V + (size_t)bh * 64 * kNtot;
  __shared__ __align__(16) char smem[34816];
  unsigned short* Elds = (unsigned short*)smem;             // [64][136]
  unsigned short* Vlds = (unsigned short*)(smem + 17408);
  int tid = threadIdx.x, lane = tid & 63, wv = tid >> 6;
  f32x4 acc[4] = {};
  float csum = 0.f;
  int cd = tid & 63, cq = tid >> 6;
  const int arow = (wv * 16 + (lane & 15)) * 136 + ((lane >> 4) << 3);
  const int brow0 = ((lane & 15)) * 136 + ((lane >> 4) << 3);

  for (int it = 0; it < 6; it++) {
    int n0 = s * 768 + it * 128;
    __syncthreads();
    #pragma unroll
    for (int r = 0; r < 4; r++) {
      int ch = r * 256 + tid;
      int d = ch >> 4, off = (ch & 15) * 8;
      *reinterpret_cast<ulonglong2*>(&Elds[d * 136 + off]) =
          *reinterpret_cast<const ulonglong2*>(Ep + (size_t)d * kNtot + n0 + off);
      *reinterpret_cast<ulonglong2*>(&Vlds[d * 136 + off]) =
          *reinterpret_cast<const ulonglong2*>(Vp + (size_t)d * kNtot + n0 + off);
    }
    __syncthreads();
    #pragma unroll
    for (int ks = 0; ks < 4; ks++) {
      bf16x8 af = *reinterpret_cast<const bf16x8*>(&Elds[arow + ks * 32]);
      #pragma unroll
      for (int j = 0; j < 4; j++) {
        bf16x8 bf = *reinterpret_cast<const bf16x8*>(&Vlds[brow0 + j * 16 * 136 + ks * 32]);
        acc[j] = __builtin_amdgcn_mfma_f32_16x16x32_bf16(af, bf, acc[j], 0, 0, 0);
      }
    }
    #pragma unroll
    for (int k8 = 0; k8 < 4; k8++) {
      bf16x8 ev = *reinterpret_cast<const bf16x8*>(&Elds[cd * 136 + cq * 32 + k8 * 8]);
      const unsigned short* pu = reinterpret_cast<const unsigned short*>(&ev);
      #pragma unroll
      for (int e = 0; e < 8; e++) csum += bf2f(pu[e]);
    }
  }
  float* op = part + ((size_t)bh * kNS2 + s) * 4096;
  int dbase = wv * 16 + ((lane >> 4) << 2);
  #pragma unroll
  for (int j = 0; j < 4; j++)
    #pragma unroll
    for (int r = 0; r < 4; r++)
      op[(dbase + r) * 64 + j * 16 + (lane & 15)] = acc[j][r];
  __syncthreads();
  float* csu = (float*)smem;
  csu[cq * 64 + cd] = csum;
  __syncthreads();
  if (tid < 64)
    part_cs[((size_t)bh * kNS2 + s) * 64 + tid] =
        csu[tid] + csu[64 + tid] + csu[128 + tid] + csu[192 + tid];
}

// ---- combine partials, apply 1/colsum, write att^T bf16 [l][d] ----
__global__ __launch_bounds__(256) void attc_kernel(const float* __restrict__ part,
    const float* __restrict__ part_cs, unsigned short* __restrict__ attT) {
  int bh = blockIdx.x;
  __shared__ float at[64][65];
  __shared__ float sinv[64];
  int tid = threadIdx.x;
  if (tid < 64) {
    float s = 0.f;
    #pragma unroll
    for (int c = 0; c < kNS2; c++) s += part_cs[((size_t)bh * kNS2 + c) * 64 + tid];
    sinv[tid] = 1.f / s;
  }
  for (int i = tid; i < 4096; i += 256) {
    float s = 0.f;
    #pragma unroll
    for (int c = 0; c < kNS2; c++) s += part[((size_t)bh * kNS2 + c) * 4096 + i];
    at[i >> 6][i & 63] = s;
  }
  __syncthreads();
  for (int j = tid; j < 4096; j += 256) {
    int l = j >> 6, d = j & 63;
    attT[(size_t)bh * 4096 + j] = f2bf(at[d][l] * sinv[d]);
  }
}

// ---- y = (expq/rowsum) @ att via MFMA; y bf16 ----
__global__ __launch_bounds__(256) void y_mfma(const unsigned short* __restrict__ q,
    const unsigned short* __restrict__ attT, unsigned short* __restrict__ y) {
  int bh = blockIdx.x; int b = bh >> 3, h = bh & 7;
  int t0 = blockIdx.y * 128;
  __shared__ unsigned short bt[64][72];
  __shared__ float rs[128];
  __shared__ unsigned short ob[128][72];
  int tid = threadIdx.x, lane = tid & 63, wv = tid >> 6;
  int wr = wv * 32;
  for (int i = tid; i < 512; i += 256) {
    int row = i >> 3, c8 = (i & 7) * 8;
    *reinterpret_cast<ulonglong2*>(&bt[row][c8]) =
        *reinterpret_cast<const ulonglong2*>(attT + (size_t)bh * 4096 + row * 64 + c8);
  }
  const unsigned short* qp = q + ((size_t)(b * 1024 + t0 + wr)) * 512 + h * 64;
  bf16x8 af[2][2];
  #pragma unroll
  for (int i = 0; i < 2; i++) {
    int row = i * 16 + (lane & 15);
    #pragma unroll
    for (int s = 0; s < 2; s++)
      af[i][s] = *reinterpret_cast<const bf16x8*>(qp + (size_t)row * 512 + s * 32 + (lane >> 4) * 8);
  }
  #pragma unroll
  for (int i = 0; i < 2; i++) {
    float r = 0.f;
    #pragma unroll
    for (int s = 0; s < 2; s++) {
      const unsigned short* pu = reinterpret_cast<const unsigned short*>(&af[i][s]);
      #pragma unroll
      for (int e = 0; e < 8; e++) r += bf2f(pu[e]);
    }
    r += __shfl_xor(r, 16); r += __shfl_xor(r, 32);
    if (lane < 16) rs[wr + i * 16 + lane] = r;
  }
  __syncthreads();
  f32x4 acc[2][4] = {};
  #pragma unroll
  for (int s = 0; s < 2; s++) {
    #pragma unroll
    for (int j = 0; j < 4; j++) {
      bf16x8 bf = *reinterpret_cast<const bf16x8*>(&bt[j * 16 + (lane & 15)][s * 32 + (lane >> 4) * 8]);
      #pragma unroll
      for (int i = 0; i < 2; i++)
        acc[i][j] = __builtin_amdgcn_mfma_f32_16x16x32_bf16(af[i][s], bf, acc[i][j], 0, 0, 0);
    }
  }
  int r4 = (lane >> 4) << 2;
  #pragma unroll
  for (int i = 0; i < 2; i++) {
    #pragma unroll
    for (int r = 0; r < 4; r++) {
      int row = wr + i * 16 + r4 + r;
      float rinv = 1.f / rs[row];
      #pragma unroll
      for (int j = 0; j < 4; j++)
        ob[row][j * 16 + (lane & 15)] = f2bf(acc[i][j][r] * rinv);
    }
  }
  __syncthreads();
  for (int i = tid; i < 1024; i += 256) {
    int row = i >> 3, c8 = (i & 7) * 8;
    *reinterpret_cast<ulonglong2*>(y + ((size_t)(b * 1024 + t0 + row)) * 512 + h * 64 + c8) =
        *reinterpret_cast<const ulonglong2*>(&ob[row][c8]);
  }
}

// ---------------- LN(y)*(1+scale)+shift then SiLU -> bf16 ----------------
__global__ __launch_bounds__(256) void mod_kernel(const unsigned short* __restrict__ y,
    const float* __restrict__ ss, const float* __restrict__ g, const float* __restrict__ be,
    unsigned short* __restrict__ h) {
  int row = blockIdx.x; int b = row >> 10;
  const unsigned short* p = y + (size_t)row * 512;
  unsigned short* o = h + (size_t)row * 512;
  float v[2]; float s = 0.f, s2 = 0.f;
  #pragma unroll
  for (int i = 0; i < 2; i++) {
    v[i] = bf2f(p[threadIdx.x + i * 256]);
    s += v[i]; s2 += v[i] * v[i];
  }
  __shared__ float red[2][4];
  int lane = threadIdx.x & 63, w = threadIdx.x >> 6;
  s = wave_sum(s); s2 = wave_sum(s2);
  if (!lane) { red[0][w] = s; red[1][w] = s2; }
  __syncthreads();
  s = red[0][0] + red[0][1] + red[0][2] + red[0][3];
  s2 = red[1][0] + red[1][1] + red[1][2] + red[1][3];
  float mean = s / 512.f, var = s2 / 512.f - mean * mean;
  float rstd = rsqrtf(var + 1e-5f);
  #pragma unroll
  for (int i = 0; i < 2; i++) {
    int c = threadIdx.x + i * 256;
    float val = (v[i] - mean) * rstd * g[c] + be[c];
    val = val * (1.f + ss[b * 1024 + c]) + ss[b * 1024 + 512 + c];
    o[c] = f2bf(val / (1.f + __expf(-val)));
  }
}

}  // namespace

extern "C" void kernel_launch(void* const* d_in, const int* in_sizes, int n_in,
                              void* d_out, int out_size, void* d_ws, size_t ws_size,
                              hipStream_t stream) {
  const float* x        = (const float*)d_in[0];
  const float* xf       = (const float*)d_in[1];
  const float* emb      = (const float*)d_in[2];
  const float* src_mask = (const float*)d_in[3];
  const int*   cond     = (const int*)d_in[4];
  const float* re_motion= (const float*)d_in[5];
  const float* re_text  = (const float*)d_in[6];
  const float* re_mask  = (const float*)d_in[7];
  const float* norm_g = (const float*)d_in[8],  * norm_b = (const float*)d_in[9];
  const float* tnorm_g= (const float*)d_in[10], * tnorm_b= (const float*)d_in[11];
  const float* rn1_g  = (const float*)d_in[12], * rn1_b  = (const float*)d_in[13];
  const float* rn2_g  = (const float*)d_in[14], * rn2_b  = (const float*)d_in[15];
  const float* Wq  = (const float*)d_in[16], * bq  = (const float*)d_in[17];
  const float* Wkt = (const float*)d_in[18], * bkt = (const float*)d_in[19];
  const float* Wvt = (const float*)d_in[20], * bvt = (const float*)d_in[21];
  const float* Wkm = (const float*)d_in[22], * bkm = (const float*)d_in[23];
  const float* Wvm = (const float*)d_in[24], * bvm = (const float*)d_in[25];
  const float* Wkr = (const float*)d_in[26], * bkr = (const float*)d_in[27];
  const float* Wvr = (const float*)d_in[28], * bvr = (const float*)d_in[29];
  const float* emb_W = (const float*)d_in[30], * emb_b = (const float*)d_in[31];
  const float* snorm_g = (const float*)d_in[32], * snorm_b = (const float*)d_in[33];
  const float* out_W = (const float*)d_in[34], * out_b = (const float*)d_in[35];
  float* out = (float*)d_out;

  char* base = (char*)d_ws;
  size_t off = 0;
  auto ab = [&](size_t nb) { char* p = base + off; off = (off + nb + 255) & ~(size_t)255; return p; };

  unsigned short* wcat0 = (unsigned short*)ab((size_t)1536 * 512 * 2);  // Wq|Wkm|Wvm
  unsigned short* wcat1 = (unsigned short*)ab((size_t)1024 * 512 * 2);  // W'kr|W'vr
  unsigned short* wcat2 = (unsigned short*)ab((size_t)1024 * 256 * 2);  // Wkt|Wvt
  unsigned short* wout_bf= (unsigned short*)ab(512 * 512 * 2);
  float* G1 = (float*)ab(512 * 4); float* B1 = (float*)ab(512 * 4);
  float* G2 = (float*)ab(512 * 4); float* B2 = (float*)ab(512 * 4);
  float* Tbuf = (float*)ab((size_t)kB * kR * 512 * 4);
  float* semb_f   = (float*)ab((size_t)kB * 2048 * 4);
  float* part_emb = (float*)ab((size_t)8 * kB * 1024 * 4);
  float* ssb_full = (float*)ab((size_t)kB * 1024 * 4);
  float* kaT_full = (float*)ab((size_t)kB * kNT * 4);
  float* vmT_full = (float*)ab((size_t)kB * kNT * 4);
  float* kaR_full = (float*)ab((size_t)kB * kRL * 4);
  float* kaM_full = (float*)ab((size_t)kB * kT * 4);
  float* vmR_full = (float*)ab((size_t)kB * kRL * 4);
  float* vmM_full = (float*)ab((size_t)kB * kT * 4);
  const size_t fixed_off = off;

  auto pad = [](size_t n) { return (n + 255) & ~(size_t)255; };
  auto att_bytes = [&](size_t CH) -> size_t {
    return pad(CH * 8 * 4096 * 2)
         + pad(CH * 8 * (size_t)kNS2 * 4096 * 4)
         + pad(CH * 8 * (size_t)kNS2 * 64 * 4);
  };
  auto chunk_bytes = [&](size_t CH) -> size_t {
    size_t xnr = pad(CH * 1024 * 512 * 2);
    if (att_bytes(CH) > xnr) xnr = att_bytes(CH);
    size_t s = 0;
    s += xnr;
    s += pad(CH * kNT * 256 * 2);
    s += pad(CH * 1024 * 512 * 2);
    s += 4 * pad(CH * 1024 * 4);
    s += pad(CH * 1024 * 512 * 2);
    s += pad((size_t)CH * 512 * kNtot * 2);
    s += pad((size_t)CH * 512 * kNtot * 2);
    return s;
  };
  int CH = 32;
  while (CH > 1 && fixed_off + chunk_bytes(CH) > ws_size) CH >>= 1;

  auto cl = [&](const float* s, unsigned short* d, int n) {
    castw<<<dim3((n / 4 + 255) / 256), 256, 0, stream>>>(s, d, n);
  };
  cl(Wq,  wcat0,              512 * 512);
  cl(Wkm, wcat0 + 512 * 512,  512 * 512);
  cl(Wvm, wcat0 + 1024 * 512, 512 * 512);
  cl(Wkt, wcat2,              512 * 256);
  cl(Wvt, wcat2 + 512 * 256,  512 * 256);
  cl(out_W, wout_bf, 512 * 512);
  prep_w<<<dim3(512), 256, 0, stream>>>(Wkr, rn1_g, rn1_b, bkr, Wvr, rn2_g, rn2_b, bvr,
                                        wcat1, wcat1 + 512 * 512, G1, B1, G2, B2);
  text_T<<<dim3(kB * kR, 8), 256, 0, stream>>>(re_text, rn1_g, Wkr, Tbuf);

  rowmask_kernel<<<dim3(kB * 4), 256, 0, stream>>>(cond, src_mask, re_mask,
      kaT_full, kaR_full, kaM_full, vmT_full, vmR_full, vmM_full, kB);
  silu_emb<<<dim3(kB * 2048 / 1024), 256, 0, stream>>>(emb, semb_f);
  emb_gemv2<<<dim3(256, 8), 256, 0, stream>>>(semb_f, emb_W, part_emb);
  emb_fin<<<dim3(128), 256, 0, stream>>>(part_emb, emb_b, ssb_full);

  for (int b0 = 0; b0 < kB; b0 += CH) {
    off = fixed_off;
    const int MRc = CH * 1024;
    const int MTc = CH * kNT;

    size_t xnr = pad((size_t)MRc * 512 * 2);
    if (att_bytes(CH) > xnr) xnr = att_bytes(CH);
    char* xnR = ab(xnr);
    unsigned short* xn_bf  = (unsigned short*)xnR;
    unsigned short* attT = (unsigned short*)xnR;
    float* attp = (float*)(xnR + pad((size_t)CH * 8 * 4096 * 2));
    float* part_cs = (float*)(xnR + pad((size_t)CH * 8 * 4096 * 2)
                                  + pad((size_t)CH * 8 * (size_t)kNS2 * 4096 * 4));
    unsigned short* h_bf = xn_bf;

    unsigned short* xfn_bf = (unsigned short*)ab((size_t)MTc * 256 * 2);
    unsigned short* mot_bf = (unsigned short*)ab((size_t)MRc * 512 * 2);
    float* s1k = (float*)ab((size_t)CH * 1024 * 4);
    float* s2k = (float*)ab((size_t)CH * 1024 * 4);
    float* s1v = (float*)ab((size_t)CH * 1024 * 4);
    float* s2v = (float*)ab((size_t)CH * 1024 * 4);
    unsigned short* qb_bf  = (unsigned short*)ab((size_t)MRc * 512 * 2);
    unsigned short* kc_bf  = (unsigned short*)ab((size_t)CH * 512 * kNtot * 2);
    unsigned short* vb_bf  = (unsigned short*)ab((size_t)CH * 512 * kNtot * 2);
    unsigned short* yb16 = mot_bf;

    const float* x_c   = x + (size_t)b0 * kT * 512;
    const float* xf_c  = xf + (size_t)b0 * kNT * 256;
    const float* rm_c  = re_motion + (size_t)b0 * kRL * 512;
    const float* rt_c  = re_text + (size_t)b0 * kR * 512;
    float* out_c = out + (size_t)b0 * kT * 512;

    // --- preprocessing ---
    ln_bf16<512><<<dim3(MRc), 256, 0, stream>>>(x_c, norm_g, norm_b, xn_bf);
    ln_bf16<256><<<dim3(MTc), 256, 0, stream>>>(xf_c, tnorm_g, tnorm_b, xfn_bf);
    rfk_stats<<<dim3(MRc), 256, 0, stream>>>(rm_c, rt_c, mot_bf, s1k, s2k, s1v, s2v);
    zpad_kernel<<<dim3(CH * 48), 256, 0, stream>>>(kc_bf, vb_bf, CH * 512);

    // --- merged fused projections (one launch, per-range XCD swizzle) ---
    int g0c = 12 * (MRc / 128);
    int g1c = 8 * (MRc / 128);
    int g2c = 8 * ((MTc + 127) / 128);
    gemm_fused_all<<<dim3(g0c + g1c + g2c), 256, 0, stream>>>(
        g0c, g1c,
        xn_bf, mot_bf, xfn_bf, wcat0, wcat1, wcat2,
        MRc, MTc,
        qb_bf, kc_bf, vb_bf,
        bq, bkm, bvm, B1, B2, bkt, bvt,
        kaM_full + (size_t)b0 * kT, vmM_full + (size_t)b0 * kT,
        kaR_full + (size_t)b0 * kRL, vmR_full + (size_t)b0 * kRL,
        kaT_full + (size_t)b0 * kNT, vmT_full + (size_t)b0 * kNT,
        s1k, s2k, s1v, s2v, G1, G2, Tbuf + (size_t)b0 * kR * 512);

    // --- attention ---
    attp_kernel<<<dim3(CH * 8, kNS2), 256, 0, stream>>>(kc_bf, vb_bf, attp, part_cs);
    attc_kernel<<<dim3(CH * 8), 256, 0, stream>>>(attp, part_cs, attT);
    y_mfma<<<dim3(CH * 8, 8), 256, 0, stream>>>(qb_bf, attT, yb16);

    // --- modulation + output projection with fused residual ---
    mod_kernel<<<dim3(MRc), 256, 0, stream>>>(yb16, ssb_full + (size_t)b0 * 1024,
                                              snorm_g, snorm_b, h_bf);
    gemm_mfma<<<dim3(4 * CH * 8), 256, 0, stream>>>(h_bf, wout_bf, out_b,
                                                    x_c, out_c, MRc, 512);
  }
}

// Round 25
// 503.995 us; speedup vs baseline: 1.0790x; 1.0790x over previous
//
#include <hip/hip_runtime.h>
#include <cstddef>
#include <cstdint>

#define DEV __device__ __forceinline__

namespace {

constexpr int kH = 8;
constexpr int kB = 32, kT = 1024, kNT = 77, kR = 4, kLR = 256;
constexpr int kRL = kR * kLR;            // 1024
constexpr float kNEG = -1000000.0f;
constexpr int kNtot = 2304;              // padded n per (b,h,d) row (3*768)
constexpr int kNS2 = 3;                  // attention slices of 768 n

typedef __bf16 bf16x8 __attribute__((ext_vector_type(8)));
typedef float f32x4 __attribute__((ext_vector_type(4)));

DEV unsigned short f2bf(float f) {
  unsigned int u = __float_as_uint(f);
  u += 0x7fffu + ((u >> 16) & 1u);
  return (unsigned short)(u >> 16);
}
DEV float bf2f(unsigned short h) { return __uint_as_float(((unsigned int)h) << 16); }

DEV float wave_sum(float v) {
  #pragma unroll
  for (int s = 32; s; s >>= 1) v += __shfl_xor(v, s);
  return v;
}

// XCD-aware bijective swizzle (T1): contiguous grid chunk per XCD.
DEV int xcd_swz(int bid, int nwg) {
  if ((nwg & 7) == 0) return (bid & 7) * (nwg >> 3) + (bid >> 3);
  return bid;
}

// ---------------- LayerNorm -> bf16 ----------------
template<int COLS>
__global__ __launch_bounds__(256) void ln_bf16(const float* __restrict__ in,
    const float* __restrict__ g, const float* __restrict__ be,
    unsigned short* __restrict__ out) {
  constexpr int PT = COLS / 256;
  int row = blockIdx.x;
  const float* p = in + (size_t)row * COLS;
  unsigned short* o = out + (size_t)row * COLS;
  float v[PT]; float s = 0.f, s2 = 0.f;
  #pragma unroll
  for (int i = 0; i < PT; i++) {
    v[i] = p[threadIdx.x + i * 256];
    s += v[i]; s2 += v[i] * v[i];
  }
  __shared__ float red[2][4];
  int lane = threadIdx.x & 63, w = threadIdx.x >> 6;
  s = wave_sum(s); s2 = wave_sum(s2);
  if (!lane) { red[0][w] = s; red[1][w] = s2; }
  __syncthreads();
  s = red[0][0] + red[0][1] + red[0][2] + red[0][3];
  s2 = red[1][0] + red[1][1] + red[1][2] + red[1][3];
  float mean = s / COLS;
  float var = s2 / COLS - mean * mean;
  float rstd = rsqrtf(var + 1e-5f);
  #pragma unroll
  for (int i = 0; i < PT; i++) {
    int c = threadIdx.x + i * 256;
    o[c] = f2bf((v[i] - mean) * rstd * g[c] + be[c]);
  }
}

// ---- retrieval stats: mean/rstd scalars + motion cast ----
__global__ __launch_bounds__(256) void rfk_stats(const float* __restrict__ mot,
    const float* __restrict__ txt, unsigned short* __restrict__ mot_bf,
    float* __restrict__ s1k, float* __restrict__ s2k,
    float* __restrict__ s1v, float* __restrict__ s2v) {
  int m = blockIdx.x;
  const float* pm = mot + (size_t)m * 512;
  const float* pt = txt + (size_t)(m >> 8) * 512;
  float v[2], t[2];
  float sv = 0.f, sv2 = 0.f, st = 0.f, st2 = 0.f;
  #pragma unroll
  for (int i = 0; i < 2; i++) {
    v[i] = pm[threadIdx.x + i * 256]; sv += v[i]; sv2 += v[i] * v[i];
    t[i] = pt[threadIdx.x + i * 256]; st += t[i]; st2 += t[i] * t[i];
  }
  __shared__ float red[4][4];
  int lane = threadIdx.x & 63, w = threadIdx.x >> 6;
  sv = wave_sum(sv); sv2 = wave_sum(sv2); st = wave_sum(st); st2 = wave_sum(st2);
  if (!lane) { red[0][w] = sv; red[1][w] = sv2; red[2][w] = st; red[3][w] = st2; }
  __syncthreads();
  #pragma unroll
  for (int i = 0; i < 2; i++)
    mot_bf[(size_t)m * 512 + threadIdx.x + i * 256] = f2bf(v[i]);
  if (threadIdx.x == 0) {
    float SV = red[0][0] + red[0][1] + red[0][2] + red[0][3];
    float SV2 = red[1][0] + red[1][1] + red[1][2] + red[1][3];
    float ST = red[2][0] + red[2][1] + red[2][2] + red[2][3];
    float ST2 = red[3][0] + red[3][1] + red[3][2] + red[3][3];
    float SA = SV + ST, SA2 = SV2 + ST2;
    float ma = SA / 1024.f, va = SA2 / 1024.f - ma * ma;
    float ra = rsqrtf(va + 1e-5f);
    float mv = SV / 512.f, vv = SV2 / 512.f - mv * mv;
    float rv = rsqrtf(vv + 1e-5f);
    s1k[m] = ra; s2k[m] = -ra * ma;
    s1v[m] = rv; s2v[m] = -rv * mv;
  }
}

// ---- fold LN gains into retrieval weights (into wcat1 halves); per-col constants ----
__global__ __launch_bounds__(256) void prep_w(
    const float* __restrict__ Wkr, const float* __restrict__ g1,
    const float* __restrict__ b1, const float* __restrict__ bkr,
    const float* __restrict__ Wvr, const float* __restrict__ g2,
    const float* __restrict__ b2, const float* __restrict__ bvr,
    unsigned short* __restrict__ w1lo, unsigned short* __restrict__ w2,
    float* __restrict__ G1, float* __restrict__ B1,
    float* __restrict__ G2, float* __restrict__ B2) {
  int n = blockIdx.x;   // 512
  int tid = threadIdx.x;
  float gs = 0.f, bs = 0.f;
  #pragma unroll
  for (int i = 0; i < 4; i++) {
    int k = tid + i * 256;
    float w = Wkr[(size_t)n * 1024 + k];
    float gv = g1[k];
    gs += gv * w; bs += b1[k] * w;
    if (i < 2) w1lo[(size_t)n * 512 + k] = f2bf(gv * w);
  }
  float g2s = 0.f, b2s = 0.f;
  #pragma unroll
  for (int i = 0; i < 2; i++) {
    int k = tid + i * 256;
    float w = Wvr[(size_t)n * 512 + k];
    g2s += g2[k] * w; b2s += b2[k] * w;
    w2[(size_t)n * 512 + k] = f2bf(g2[k] * w);
  }
  __shared__ float red[4][4];
  int lane = tid & 63, w_ = tid >> 6;
  gs = wave_sum(gs); bs = wave_sum(bs); g2s = wave_sum(g2s); b2s = wave_sum(b2s);
  if (!lane) { red[0][w_] = gs; red[1][w_] = bs; red[2][w_] = g2s; red[3][w_] = b2s; }
  __syncthreads();
  if (tid == 0) {
    G1[n] = red[0][0] + red[0][1] + red[0][2] + red[0][3];
    B1[n] = red[1][0] + red[1][1] + red[1][2] + red[1][3] + bkr[n];
    G2[n] = red[2][0] + red[2][1] + red[2][2] + red[2][3];
    B2[n] = red[3][0] + red[3][1] + red[3][2] + red[3][3] + bvr[n];
  }
}

// ---- T[m][n] = (g1_hi * text[m]) . Wkr[n, 512:1024] ; grid (128 m, 8 n-slices) ----
__global__ __launch_bounds__(256) void text_T(const float* __restrict__ re_text,
    const float* __restrict__ g1, const float* __restrict__ Wkr,
    float* __restrict__ T) {
  int m = blockIdx.x;
  int ns = blockIdx.y;
  __shared__ float tr[512];
  int tid = threadIdx.x;
  #pragma unroll
  for (int i = 0; i < 2; i++) {
    int k = tid + i * 256;
    tr[k] = re_text[(size_t)m * 512 + k] * g1[512 + k];
  }
  __syncthreads();
  int n = ns * 64 + (tid >> 2);
  int k0 = (tid & 3) * 128;
  const float* wp = Wkr + (size_t)n * 1024 + 512 + k0;
  float acc = 0.f;
  #pragma unroll
  for (int k = 0; k < 128; k += 4) {
    float4 w4 = *reinterpret_cast<const float4*>(wp + k);
    float4 t4 = *reinterpret_cast<const float4*>(&tr[k0 + k]);
    acc = fmaf(t4.x, w4.x, fmaf(t4.y, w4.y, fmaf(t4.z, w4.z, fmaf(t4.w, w4.w, acc))));
  }
  acc += __shfl_xor(acc, 1);
  acc += __shfl_xor(acc, 2);
  if ((tid & 3) == 0) T[(size_t)m * 512 + n] = acc;
}

// ---------------- per-row mask arrays (full batch) ----------------
__global__ __launch_bounds__(256) void rowmask_kernel(const int* __restrict__ ct,
    const float* __restrict__ src_mask, const float* __restrict__ re_mask,
    float* __restrict__ kaT, float* __restrict__ kaR, float* __restrict__ kaM,
    float* __restrict__ vmT, float* __restrict__ vmR, float* __restrict__ vmM,
    int nB) {
  int i = blockIdx.x * 256 + threadIdx.x;
  if (i < nB * kRL) {
    int b = i >> 10;
    int c = ct[b];
    float retr = (c / 10 > 0) ? 1.f : 0.f;
    float rm = re_mask[i];
    kaR[i] = (1.f - retr) * kNEG + (1.f - rm) * kNEG;
    vmR[i] = retr * rm;
    float sm = src_mask[i];
    kaM[i] = (1.f - sm) * kNEG;
    vmM[i] = sm;
  }
  if (i < nB * kNT) {
    int b = i / kNT;
    int c = ct[b];
    float text = (c % 10 > 0) ? 1.f : 0.f;
    kaT[i] = (1.f - text) * kNEG;
    vmT[i] = text;
  }
}

// ---------------- weight cast f32 -> bf16 ----------------
__global__ __launch_bounds__(256) void castw(const float* __restrict__ s,
    unsigned short* __restrict__ d, int n) {
  int i = (blockIdx.x * 256 + threadIdx.x) * 4;
  if (i < n) {
    float4 v = *reinterpret_cast<const float4*>(s + i);
    ushort4 o;
    o.x = f2bf(v.x); o.y = f2bf(v.y); o.z = f2bf(v.z); o.w = f2bf(v.w);
    *reinterpret_cast<ushort4*>(d + i) = o;
  }
}

// ---------------- zero-pad tail of E'/V' rows ----------------
__global__ __launch_bounds__(256) void zpad_kernel(unsigned short* __restrict__ E,
    unsigned short* __restrict__ V, int rows) {
  int i = blockIdx.x * 256 + threadIdx.x;
  if (i >= rows * 24) return;
  int row = i / 24, c = i % 24;
  size_t off = (size_t)row * kNtot + 2112 + c * 8;
  ulonglong2 z; z.x = 0; z.y = 0;
  *reinterpret_cast<ulonglong2*>(E + off) = z;
  *reinterpret_cast<ulonglong2*>(V + off) = z;
}

// ---------------- silu(emb) precompute (f32) ----------------
__global__ __launch_bounds__(256) void silu_emb(const float* __restrict__ emb,
    float* __restrict__ semb) {
  int i = (blockIdx.x * 256 + threadIdx.x) * 4;
  float4 v = *reinterpret_cast<const float4*>(emb + i);
  float4 o;
  o.x = v.x / (1.f + __expf(-v.x));
  o.y = v.y / (1.f + __expf(-v.y));
  o.z = v.z / (1.f + __expf(-v.z));
  o.w = v.w / (1.f + __expf(-v.w));
  *reinterpret_cast<float4*>(semb + i) = o;
}

// ---------------- emb GEMV split-K ----------------
__global__ __launch_bounds__(256) void emb_gemv2(const float* __restrict__ semb,
    const float* __restrict__ W, float* __restrict__ part) {
  int n = blockIdx.x * 4 + (threadIdx.x >> 6);
  int s = blockIdx.y;
  int lane = threadIdx.x & 63;
  int k = s * 256 + lane * 4;
  float4 wv = *reinterpret_cast<const float4*>(&W[(size_t)n * 2048 + k]);
  float acc[32];
  #pragma unroll
  for (int m = 0; m < 32; m++) {
    float4 sv = *reinterpret_cast<const float4*>(&semb[(size_t)m * 2048 + k]);
    acc[m] = fmaf(sv.x, wv.x, fmaf(sv.y, wv.y, fmaf(sv.z, wv.z, sv.w * wv.w)));
  }
  #pragma unroll
  for (int m = 0; m < 32; m++) {
    float t = wave_sum(acc[m]);
    if (lane == 0) part[((size_t)s * 32 + m) * 1024 + n] = t;
  }
}
__global__ __launch_bounds__(256) void emb_fin(const float* __restrict__ part,
    const float* __restrict__ bias, float* __restrict__ ss) {
  int i = blockIdx.x * 256 + threadIdx.x;
  float s = 0.f;
  #pragma unroll
  for (int c = 0; c < 8; c++) s += part[(size_t)c * 32768 + i];
  ss[i] = s + bias[i & 1023];
}

// ================= FUSED MFMA GEMM (shared-A, multi-W sections) =================
// 3-buffer pipelined K-loop with counted vmcnt; raw barriers (no drain).
// 1D grid, XCD-swizzled: wg = xcd_swz(bid); m-tile = wg / NX, n-tile = wg % NX.
template<int COMBO, int NX>
__global__ __launch_bounds__(256) void gemm_fused(
    const unsigned short* __restrict__ A, const unsigned short* __restrict__ W,
    int M, int K, int m_per_b, int out_off,
    unsigned short* __restrict__ qout,
    unsigned short* __restrict__ E, unsigned short* __restrict__ V,
    const float* __restrict__ biasA, const float* __restrict__ biasB,
    const float* __restrict__ biasC,
    const float* __restrict__ rowAddK, const float* __restrict__ rowMulV,
    const float* __restrict__ s1k, const float* __restrict__ s2k,
    const float* __restrict__ s1v, const float* __restrict__ s2v,
    const float* __restrict__ G1v, const float* __restrict__ G2v,
    const float* __restrict__ Tt) {
  __shared__ __align__(16) char smem[49152];   // 3x16KB staging | 32KB epilogue
  unsigned short* lds = (unsigned short*)smem;
  const int tid = threadIdx.x;
  const int lane = tid & 63;
  const int wv = tid >> 6;
  const int wr = (wv >> 1) * 64;
  const int wc = (wv & 1) * 64;
  const int wg = xcd_swz(blockIdx.x, gridDim.x);
  const int m0 = (wg / NX) * 128;
  const int n0 = (wg % NX) * 128;
  const int sec = n0 >> 9;
  const int nlo = n0 & 511;

  const unsigned short* srcA[2]; const unsigned short* srcB[2];
  int dstOff[2];
  #pragma unroll
  for (int i = 0; i < 2; i++) {
    int lin = i * 256 + tid;
    int r = lin >> 2, cl = lin & 3;
    int cs = cl ^ ((r >> 1) & 3);
    int ra = m0 + r; if (ra > M - 1) ra = M - 1;
    srcA[i] = A + (size_t)ra * K + cs * 8;
    srcB[i] = W + (size_t)(n0 + r) * K + cs * 8;
    dstOff[i] = lin * 8;
  }
  int offA[4], offB[4];
  #pragma unroll
  for (int i = 0; i < 4; i++) {
    int r = wr + i * 16 + (lane & 15);
    int c = (lane >> 4) ^ ((r >> 1) & 3);
    offA[i] = r * 32 + c * 8;
    int rb = wc + i * 16 + (lane & 15);
    int cb = (lane >> 4) ^ ((rb >> 1) & 3);
    offB[i] = rb * 32 + cb * 8;
  }

  f32x4 acc[4][4] = {};
  const int nt = K >> 5;

  #pragma unroll
  for (int i = 0; i < 2; i++) {
    __builtin_amdgcn_global_load_lds(
        (const __attribute__((address_space(1))) void*)(srcA[i]),
        (__attribute__((address_space(3))) void*)&lds[dstOff[i]], 16, 0, 0);
    __builtin_amdgcn_global_load_lds(
        (const __attribute__((address_space(1))) void*)(srcB[i]),
        (__attribute__((address_space(3))) void*)&lds[4096 + dstOff[i]], 16, 0, 0);
  }

  int cur = 0;
  for (int t = 0; t < nt; t++) {
    int nxt = cur + 1; if (nxt == 3) nxt = 0;
    if (t + 1 < nt) {
      int ko = (t + 1) << 5;
      #pragma unroll
      for (int i = 0; i < 2; i++) {
        __builtin_amdgcn_global_load_lds(
            (const __attribute__((address_space(1))) void*)(srcA[i] + ko),
            (__attribute__((address_space(3))) void*)&lds[nxt * 8192 + dstOff[i]], 16, 0, 0);
        __builtin_amdgcn_global_load_lds(
            (const __attribute__((address_space(1))) void*)(srcB[i] + ko),
            (__attribute__((address_space(3))) void*)&lds[nxt * 8192 + 4096 + dstOff[i]], 16, 0, 0);
      }
      asm volatile("s_waitcnt vmcnt(4)" ::: "memory");
    } else {
      asm volatile("s_waitcnt vmcnt(0)" ::: "memory");
    }
    __builtin_amdgcn_s_barrier();
    __builtin_amdgcn_sched_barrier(0);
    bf16x8 af[4], bf[4];
    #pragma unroll
    for (int i = 0; i < 4; i++) {
      af[i] = *reinterpret_cast<const bf16x8*>(&lds[cur * 8192 + offA[i]]);
      bf[i] = *reinterpret_cast<const bf16x8*>(&lds[cur * 8192 + 4096 + offB[i]]);
    }
    #pragma unroll
    for (int i = 0; i < 4; i++)
      #pragma unroll
      for (int j = 0; j < 4; j++)
        acc[i][j] = __builtin_amdgcn_mfma_f32_16x16x32_bf16(af[i], bf[j], acc[i][j], 0, 0, 0);
    cur = nxt;
  }
  __syncthreads();   // all loads done; sync before epilogue reuses LDS

  const int r4 = (lane >> 4) << 2;
  const int rowb = m0 + wr + r4;

  auto epival = [&](float accv, int rowg, int cl) -> float {
    if (COMBO == 0) {
      if (sec == 0) return __expf(accv + biasA[cl]);
      if (sec == 1) return __expf(accv + biasB[cl] + rowAddK[rowg]);
      return (accv + biasC[cl]) * rowMulV[rowg];
    } else if (COMBO == 1) {
      if (sec == 0)
        return __expf((accv + Tt[(size_t)(rowg >> 8) * 512 + cl]) * s1k[rowg]
                      + s2k[rowg] * G1v[cl] + biasA[cl] + rowAddK[rowg]);
      return (accv * s1v[rowg] + s2v[rowg] * G2v[cl] + biasB[cl]) * rowMulV[rowg];
    } else {
      if (sec == 0) return __expf(accv + biasA[cl] + rowAddK[rowg]);
      return (accv + biasB[cl]) * rowMulV[rowg];
    }
  };

  unsigned short* dstEV = (COMBO == 0) ? (sec == 1 ? E : V) : (sec == 0 ? E : V);

  if (COMBO == 2) {
    // scalar transposed epilogue (m_per_b = 77)
    #pragma unroll
    for (int i = 0; i < 4; i++) {
      #pragma unroll
      for (int r = 0; r < 4; r++) {
        int row = rowb + i * 16 + r;
        if (row >= M) continue;
        size_t nn = out_off + (row % m_per_b);
        size_t cb = (size_t)(row / m_per_b) * 512;
        #pragma unroll
        for (int j = 0; j < 4; j++) {
          int cl = nlo + wc + j * 16 + (lane & 15);
          dstEV[(cb + cl) * kNtot + nn] = f2bf(epival(acc[i][j][r], row, cl));
        }
      }
    }
    return;
  }

  // staged epilogue [128][128] bf16, XOR-keyed
  unsigned short* S = (unsigned short*)smem;
  #pragma unroll
  for (int i = 0; i < 4; i++) {
    #pragma unroll
    for (int r = 0; r < 4; r++) {
      int row_t = wr + i * 16 + r4 + r;
      int rowg = m0 + row_t; if (rowg > M - 1) rowg = M - 1;
      int key = ((row_t >> 3) & 7) << 3;
      #pragma unroll
      for (int j = 0; j < 4; j++) {
        int col_t = wc + j * 16 + (lane & 15);
        S[row_t * 128 + (col_t ^ key)] = f2bf(epival(acc[i][j][r], rowg, nlo + col_t));
      }
    }
  }
  __syncthreads();
  bool linear = (COMBO == 0 && sec == 0);
  if (linear) {
    #pragma unroll
    for (int it = 0; it < 8; it++) {
      int slot = it * 256 + tid;
      int row_t = slot >> 4;
      int cs = (slot & 15) * 8;
      int key = ((row_t >> 3) & 7) << 3;
      int row = m0 + row_t;
      if (row < M) {
        ulonglong2 d = *reinterpret_cast<const ulonglong2*>(&S[row_t * 128 + (cs ^ key)]);
        *reinterpret_cast<ulonglong2*>(qout + (size_t)row * 512 + nlo + cs) = d;
      }
    }
  } else {
    #pragma unroll
    for (int it = 0; it < 8; it++) {
      int slot = it * 256 + tid;
      int col_t = slot >> 4;
      int mcx = slot & 15;
      int mc = mcx * 8;
      int key = (mcx & 7) << 3;
      union { unsigned short u[8]; ulonglong2 v; } w;
      #pragma unroll
      for (int e = 0; e < 8; e++)
        w.u[e] = S[(mc + e) * 128 + (col_t ^ key)];
      int row = m0 + mc;   // M % 128 == 0 here
      size_t obase = ((size_t)(row / m_per_b) * 512 + nlo + col_t) * (size_t)kNtot
                   + out_off + (row % m_per_b);
      *reinterpret_cast<ulonglong2*>(dstEV + obase) = w.v;
    }
  }
}

// ------- plain MFMA GEMM (final projection) + fused residual: out = x + (C+bias) -------
__global__ __launch_bounds__(256) void gemm_mfma(
    const unsigned short* __restrict__ A, const unsigned short* __restrict__ W,
    const float* __restrict__ bias, const float* __restrict__ Xres,
    float* __restrict__ Outf, int M, int K) {
  __shared__ __align__(16) char smem[49152];
  unsigned short* lds = (unsigned short*)smem;
  const int tid = threadIdx.x;
  const int lane = tid & 63;
  const int wv = tid >> 6;
  const int wr = (wv >> 1) * 64;
  const int wc = (wv & 1) * 64;
  const int wg = xcd_swz(blockIdx.x, gridDim.x);
  const int m0 = (wg >> 2) * 128;
  const int n0 = (wg & 3) * 128;

  const unsigned short* srcA[2]; const unsigned short* srcB[2];
  int dstOff[2];
  #pragma unroll
  for (int i = 0; i < 2; i++) {
    int lin = i * 256 + tid;
    int r = lin >> 2, cl = lin & 3;
    int cs = cl ^ ((r >> 1) & 3);
    int ra = m0 + r; if (ra > M - 1) ra = M - 1;
    srcA[i] = A + (size_t)ra * K + cs * 8;
    srcB[i] = W + (size_t)(n0 + r) * K + cs * 8;
    dstOff[i] = lin * 8;
  }
  int offA[4], offB[4];
  #pragma unroll
  for (int i = 0; i < 4; i++) {
    int r = wr + i * 16 + (lane & 15);
    int c = (lane >> 4) ^ ((r >> 1) & 3);
    offA[i] = r * 32 + c * 8;
    int rb = wc + i * 16 + (lane & 15);
    int cb = (lane >> 4) ^ ((rb >> 1) & 3);
    offB[i] = rb * 32 + cb * 8;
  }

  f32x4 acc[4][4] = {};
  const int nt = K >> 5;

  #pragma unroll
  for (int i = 0; i < 2; i++) {
    __builtin_amdgcn_global_load_lds(
        (const __attribute__((address_space(1))) void*)(srcA[i]),
        (__attribute__((address_space(3))) void*)&lds[dstOff[i]], 16, 0, 0);
    __builtin_amdgcn_global_load_lds(
        (const __attribute__((address_space(1))) void*)(srcB[i]),
        (__attribute__((address_space(3))) void*)&lds[4096 + dstOff[i]], 16, 0, 0);
  }

  int cur = 0;
  for (int t = 0; t < nt; t++) {
    int nxt = cur + 1; if (nxt == 3) nxt = 0;
    if (t + 1 < nt) {
      int ko = (t + 1) << 5;
      #pragma unroll
      for (int i = 0; i < 2; i++) {
        __builtin_amdgcn_global_load_lds(
            (const __attribute__((address_space(1))) void*)(srcA[i] + ko),
            (__attribute__((address_space(3))) void*)&lds[nxt * 8192 + dstOff[i]], 16, 0, 0);
        __builtin_amdgcn_global_load_lds(
            (const __attribute__((address_space(1))) void*)(srcB[i] + ko),
            (__attribute__((address_space(3))) void*)&lds[nxt * 8192 + 4096 + dstOff[i]], 16, 0, 0);
      }
      asm volatile("s_waitcnt vmcnt(4)" ::: "memory");
    } else {
      asm volatile("s_waitcnt vmcnt(0)" ::: "memory");
    }
    __builtin_amdgcn_s_barrier();
    __builtin_amdgcn_sched_barrier(0);
    bf16x8 af[4], bf[4];
    #pragma unroll
    for (int i = 0; i < 4; i++) {
      af[i] = *reinterpret_cast<const bf16x8*>(&lds[cur * 8192 + offA[i]]);
      bf[i] = *reinterpret_cast<const bf16x8*>(&lds[cur * 8192 + 4096 + offB[i]]);
    }
    #pragma unroll
    for (int i = 0; i < 4; i++)
      #pragma unroll
      for (int j = 0; j < 4; j++)
        acc[i][j] = __builtin_amdgcn_mfma_f32_16x16x32_bf16(af[i], bf[j], acc[i][j], 0, 0, 0);
    cur = nxt;
  }
  __syncthreads();

  const int r4 = (lane >> 4) << 2;
  unsigned short* S = (unsigned short*)smem;
  #pragma unroll
  for (int i = 0; i < 4; i++) {
    #pragma unroll
    for (int r = 0; r < 4; r++) {
      int row_t = wr + i * 16 + r4 + r;
      int key = ((row_t >> 3) & 7) << 3;
      #pragma unroll
      for (int j = 0; j < 4; j++) {
        int col_t = wc + j * 16 + (lane & 15);
        S[row_t * 128 + (col_t ^ key)] = f2bf(acc[i][j][r] + bias[n0 + col_t]);
      }
    }
  }
  __syncthreads();
  #pragma unroll
  for (int it = 0; it < 8; it++) {
    int slot = it * 256 + tid;
    int row_t = slot >> 4;
    int cs = (slot & 15) * 8;
    int key = ((row_t >> 3) & 7) << 3;
    int row = m0 + row_t;
    if (row < M) {
      union { unsigned short u[8]; ulonglong2 v; } w;
      w.v = *reinterpret_cast<const ulonglong2*>(&S[row_t * 128 + (cs ^ key)]);
      const float* xp = Xres + (size_t)row * 512 + n0 + cs;
      float4 x0 = *reinterpret_cast<const float4*>(xp);
      float4 x1 = *reinterpret_cast<const float4*>(xp + 4);
      float4 o0, o1;
      o0.x = x0.x + bf2f(w.u[0]); o0.y = x0.y + bf2f(w.u[1]);
      o0.z = x0.z + bf2f(w.u[2]); o0.w = x0.w + bf2f(w.u[3]);
      o1.x = x1.x + bf2f(w.u[4]); o1.y = x1.y + bf2f(w.u[5]);
      o1.z = x1.z + bf2f(w.u[6]); o1.w = x1.w + bf2f(w.u[7]);
      float* op = Outf + (size_t)row * 512 + n0 + cs;
      *reinterpret_cast<float4*>(op) = o0;
      *reinterpret_cast<float4*>(op + 4) = o1;
    }
  }
}

// ---- attention partials via MFMA (NT form), wave-per-d-slab ----
__global__ __launch_bounds__(256) void attp_kernel(const unsigned short* __restrict__ E,
    const unsigned short* __restrict__ V, float* __restrict__ part,
    float* __restrict__ part_cs) {
  int bh = blockIdx.x;
  int s = blockIdx.y;
  const unsigned short* Ep = E + (size_t)bh * 64 * kNtot;
  const unsigned short* Vp = V + (size_t)bh * 64 * kNtot;
  __shared__ __align__(16) char smem[34816];
  unsigned short* Elds = (unsigned short*)smem;             // [64][136]
  unsigned short* Vlds = (unsigned short*)(smem + 17408);
  int tid = threadIdx.x, lane = tid & 63, wv = tid >> 6;
  f32x4 acc[4] = {};
  float csum = 0.f;
  int cd = tid & 63, cq = tid >> 6;
  const int arow = (wv * 16 + (lane & 15)) * 136 + ((lane >> 4) << 3);
  const int brow0 = ((lane & 15)) * 136 + ((lane >> 4) << 3);

  for (int it = 0; it < 6; it++) {
    int n0 = s * 768 + it * 128;
    __syncthreads();
    #pragma unroll
    for (int r = 0; r < 4; r++) {
      int ch = r * 256 + tid;
      int d = ch >> 4, off = (ch & 15) * 8;
      *reinterpret_cast<ulonglong2*>(&Elds[d * 136 + off]) =
          *reinterpret_cast<const ulonglong2*>(Ep + (size_t)d * kNtot + n0 + off);
      *reinterpret_cast<ulonglong2*>(&Vlds[d * 136 + off]) =
          *reinterpret_cast<const ulonglong2*>(Vp + (size_t)d * kNtot + n0 + off);
    }
    __syncthreads();
    #pragma unroll
    for (int ks = 0; ks < 4; ks++) {
      bf16x8 af = *reinterpret_cast<const bf16x8*>(&Elds[arow + ks * 32]);
      #pragma unroll
      for (int j = 0; j < 4; j++) {
        bf16x8 bf = *reinterpret_cast<const bf16x8*>(&Vlds[brow0 + j * 16 * 136 + ks * 32]);
        acc[j] = __builtin_amdgcn_mfma_f32_16x16x32_bf16(af, bf, acc[j], 0, 0, 0);
      }
    }
    #pragma unroll
    for (int k8 = 0; k8 < 4; k8++) {
      bf16x8 ev = *reinterpret_cast<const bf16x8*>(&Elds[cd * 136 + cq * 32 + k8 * 8]);
      const unsigned short* pu = reinterpret_cast<const unsigned short*>(&ev);
      #pragma unroll
      for (int e = 0; e < 8; e++) csum += bf2f(pu[e]);
    }
  }
  float* op = part + ((size_t)bh * kNS2 + s) * 4096;
  int dbase = wv * 16 + ((lane >> 4) << 2);
  #pragma unroll
  for (int j = 0; j < 4; j++)
    #pragma unroll
    for (int r = 0; r < 4; r++)
      op[(dbase + r) * 64 + j * 16 + (lane & 15)] = acc[j][r];
  __syncthreads();
  float* csu = (float*)smem;
  csu[cq * 64 + cd] = csum;
  __syncthreads();
  if (tid < 64)
    part_cs[((size_t)bh * kNS2 + s) * 64 + tid] =
        csu[tid] + csu[64 + tid] + csu[128 + tid] + csu[192 + tid];
}

// ---- combine partials, apply 1/colsum, write att^T bf16 [l][d] ----
__global__ __launch_bounds__(256) void attc_kernel(const float* __restrict__ part,
    const float* __restrict__ part_cs, unsigned short* __restrict__ attT) {
  int bh = blockIdx.x;
  __shared__ float at[64][65];
  __shared__ float sinv[64];
  int tid = threadIdx.x;
  if (tid < 64) {
    float s = 0.f;
    #pragma unroll
    for (int c = 0; c < kNS2; c++) s += part_cs[((size_t)bh * kNS2 + c) * 64 + tid];
    sinv[tid] = 1.f / s;
  }
  for (int i = tid; i < 4096; i += 256) {
    float s = 0.f;
    #pragma unroll
    for (int c = 0; c < kNS2; c++) s += part[((size_t)bh * kNS2 + c) * 4096 + i];
    at[i >> 6][i & 63] = s;
  }
  __syncthreads();
  for (int j = tid; j < 4096; j += 256) {
    int l = j >> 6, d = j & 63;
    attT[(size_t)bh * 4096 + j] = f2bf(at[d][l] * sinv[d]);
  }
}

// ---- y = (expq/rowsum) @ att via MFMA; y bf16 ----
__global__ __launch_bounds__(256) void y_mfma(const unsigned short* __restrict__ q,
    const unsigned short* __restrict__ attT, unsigned short* __restrict__ y) {
  int bh = blockIdx.x; int b = bh >> 3, h = bh & 7;
  int t0 = blockIdx.y * 128;
  __shared__ unsigned short bt[64][72];
  __shared__ float rs[128];
  __shared__ unsigned short ob[128][72];
  int tid = threadIdx.x, lane = tid & 63, wv = tid >> 6;
  int wr = wv * 32;
  for (int i = tid; i < 512; i += 256) {
    int row = i >> 3, c8 = (i & 7) * 8;
    *reinterpret_cast<ulonglong2*>(&bt[row][c8]) =
        *reinterpret_cast<const ulonglong2*>(attT + (size_t)bh * 4096 + row * 64 + c8);
  }
  const unsigned short* qp = q + ((size_t)(b * 1024 + t0 + wr)) * 512 + h * 64;
  bf16x8 af[2][2];
  #pragma unroll
  for (int i = 0; i < 2; i++) {
    int row = i * 16 + (lane & 15);
    #pragma unroll
    for (int s = 0; s < 2; s++)
      af[i][s] = *reinterpret_cast<const bf16x8*>(qp + (size_t)row * 512 + s * 32 + (lane >> 4) * 8);
  }
  #pragma unroll
  for (int i = 0; i < 2; i++) {
    float r = 0.f;
    #pragma unroll
    for (int s = 0; s < 2; s++) {
      const unsigned short* pu = reinterpret_cast<const unsigned short*>(&af[i][s]);
      #pragma unroll
      for (int e = 0; e < 8; e++) r += bf2f(pu[e]);
    }
    r += __shfl_xor(r, 16); r += __shfl_xor(r, 32);
    if (lane < 16) rs[wr + i * 16 + lane] = r;
  }
  __syncthreads();
  f32x4 acc[2][4] = {};
  #pragma unroll
  for (int s = 0; s < 2; s++) {
    #pragma unroll
    for (int j = 0; j < 4; j++) {
      bf16x8 bf = *reinterpret_cast<const bf16x8*>(&bt[j * 16 + (lane & 15)][s * 32 + (lane >> 4) * 8]);
      #pragma unroll
      for (int i = 0; i < 2; i++)
        acc[i][j] = __builtin_amdgcn_mfma_f32_16x16x32_bf16(af[i][s], bf, acc[i][j], 0, 0, 0);
    }
  }
  int r4 = (lane >> 4) << 2;
  #pragma unroll
  for (int i = 0; i < 2; i++) {
    #pragma unroll
    for (int r = 0; r < 4; r++) {
      int row = wr + i * 16 + r4 + r;
      float rinv = 1.f / rs[row];
      #pragma unroll
      for (int j = 0; j < 4; j++)
        ob[row][j * 16 + (lane & 15)] = f2bf(acc[i][j][r] * rinv);
    }
  }
  __syncthreads();
  for (int i = tid; i < 1024; i += 256) {
    int row = i >> 3, c8 = (i & 7) * 8;
    *reinterpret_cast<ulonglong2*>(y + ((size_t)(b * 1024 + t0 + row)) * 512 + h * 64 + c8) =
        *reinterpret_cast<const ulonglong2*>(&ob[row][c8]);
  }
}

// ---------------- LN(y)*(1+scale)+shift then SiLU -> bf16 ----------------
__global__ __launch_bounds__(256) void mod_kernel(const unsigned short* __restrict__ y,
    const float* __restrict__ ss, const float* __restrict__ g, const float* __restrict__ be,
    unsigned short* __restrict__ h) {
  int row = blockIdx.x; int b = row >> 10;
  const unsigned short* p = y + (size_t)row * 512;
  unsigned short* o = h + (size_t)row * 512;
  float v[2]; float s = 0.f, s2 = 0.f;
  #pragma unroll
  for (int i = 0; i < 2; i++) {
    v[i] = bf2f(p[threadIdx.x + i * 256]);
    s += v[i]; s2 += v[i] * v[i];
  }
  __shared__ float red[2][4];
  int lane = threadIdx.x & 63, w = threadIdx.x >> 6;
  s = wave_sum(s); s2 = wave_sum(s2);
  if (!lane) { red[0][w] = s; red[1][w] = s2; }
  __syncthreads();
  s = red[0][0] + red[0][1] + red[0][2] + red[0][3];
  s2 = red[1][0] + red[1][1] + red[1][2] + red[1][3];
  float mean = s / 512.f, var = s2 / 512.f - mean * mean;
  float rstd = rsqrtf(var + 1e-5f);
  #pragma unroll
  for (int i = 0; i < 2; i++) {
    int c = threadIdx.x + i * 256;
    float val = (v[i] - mean) * rstd * g[c] + be[c];
    val = val * (1.f + ss[b * 1024 + c]) + ss[b * 1024 + 512 + c];
    o[c] = f2bf(val / (1.f + __expf(-val)));
  }
}

}  // namespace

extern "C" void kernel_launch(void* const* d_in, const int* in_sizes, int n_in,
                              void* d_out, int out_size, void* d_ws, size_t ws_size,
                              hipStream_t stream) {
  const float* x        = (const float*)d_in[0];
  const float* xf       = (const float*)d_in[1];
  const float* emb      = (const float*)d_in[2];
  const float* src_mask = (const float*)d_in[3];
  const int*   cond     = (const int*)d_in[4];
  const float* re_motion= (const float*)d_in[5];
  const float* re_text  = (const float*)d_in[6];
  const float* re_mask  = (const float*)d_in[7];
  const float* norm_g = (const float*)d_in[8],  * norm_b = (const float*)d_in[9];
  const float* tnorm_g= (const float*)d_in[10], * tnorm_b= (const float*)d_in[11];
  const float* rn1_g  = (const float*)d_in[12], * rn1_b  = (const float*)d_in[13];
  const float* rn2_g  = (const float*)d_in[14], * rn2_b  = (const float*)d_in[15];
  const float* Wq  = (const float*)d_in[16], * bq  = (const float*)d_in[17];
  const float* Wkt = (const float*)d_in[18], * bkt = (const float*)d_in[19];
  const float* Wvt = (const float*)d_in[20], * bvt = (const float*)d_in[21];
  const float* Wkm = (const float*)d_in[22], * bkm = (const float*)d_in[23];
  const float* Wvm = (const float*)d_in[24], * bvm = (const float*)d_in[25];
  const float* Wkr = (const float*)d_in[26], * bkr = (const float*)d_in[27];
  const float* Wvr = (const float*)d_in[28], * bvr = (const float*)d_in[29];
  const float* emb_W = (const float*)d_in[30], * emb_b = (const float*)d_in[31];
  const float* snorm_g = (const float*)d_in[32], * snorm_b = (const float*)d_in[33];
  const float* out_W = (const float*)d_in[34], * out_b = (const float*)d_in[35];
  float* out = (float*)d_out;

  char* base = (char*)d_ws;
  size_t off = 0;
  auto ab = [&](size_t nb) { char* p = base + off; off = (off + nb + 255) & ~(size_t)255; return p; };

  unsigned short* wcat0 = (unsigned short*)ab((size_t)1536 * 512 * 2);  // Wq|Wkm|Wvm
  unsigned short* wcat1 = (unsigned short*)ab((size_t)1024 * 512 * 2);  // W'kr|W'vr
  unsigned short* wcat2 = (unsigned short*)ab((size_t)1024 * 256 * 2);  // Wkt|Wvt
  unsigned short* wout_bf= (unsigned short*)ab(512 * 512 * 2);
  float* G1 = (float*)ab(512 * 4); float* B1 = (float*)ab(512 * 4);
  float* G2 = (float*)ab(512 * 4); float* B2 = (float*)ab(512 * 4);
  float* Tbuf = (float*)ab((size_t)kB * kR * 512 * 4);
  float* semb_f   = (float*)ab((size_t)kB * 2048 * 4);
  float* part_emb = (float*)ab((size_t)8 * kB * 1024 * 4);
  float* ssb_full = (float*)ab((size_t)kB * 1024 * 4);
  float* kaT_full = (float*)ab((size_t)kB * kNT * 4);
  float* vmT_full = (float*)ab((size_t)kB * kNT * 4);
  float* kaR_full = (float*)ab((size_t)kB * kRL * 4);
  float* kaM_full = (float*)ab((size_t)kB * kT * 4);
  float* vmR_full = (float*)ab((size_t)kB * kRL * 4);
  float* vmM_full = (float*)ab((size_t)kB * kT * 4);
  const size_t fixed_off = off;

  auto pad = [](size_t n) { return (n + 255) & ~(size_t)255; };
  auto att_bytes = [&](size_t CH) -> size_t {
    return pad(CH * 8 * 4096 * 2)
         + pad(CH * 8 * (size_t)kNS2 * 4096 * 4)
         + pad(CH * 8 * (size_t)kNS2 * 64 * 4);
  };
  auto chunk_bytes = [&](size_t CH) -> size_t {
    size_t xnr = pad(CH * 1024 * 512 * 2);
    if (att_bytes(CH) > xnr) xnr = att_bytes(CH);
    size_t s = 0;
    s += xnr;
    s += pad(CH * kNT * 256 * 2);
    s += pad(CH * 1024 * 512 * 2);
    s += 4 * pad(CH * 1024 * 4);
    s += pad(CH * 1024 * 512 * 2);
    s += pad((size_t)CH * 512 * kNtot * 2);
    s += pad((size_t)CH * 512 * kNtot * 2);
    return s;
  };
  int CH = 32;
  while (CH > 1 && fixed_off + chunk_bytes(CH) > ws_size) CH >>= 1;

  auto cl = [&](const float* s, unsigned short* d, int n) {
    castw<<<dim3((n / 4 + 255) / 256), 256, 0, stream>>>(s, d, n);
  };
  cl(Wq,  wcat0,              512 * 512);
  cl(Wkm, wcat0 + 512 * 512,  512 * 512);
  cl(Wvm, wcat0 + 1024 * 512, 512 * 512);
  cl(Wkt, wcat2,              512 * 256);
  cl(Wvt, wcat2 + 512 * 256,  512 * 256);
  cl(out_W, wout_bf, 512 * 512);
  prep_w<<<dim3(512), 256, 0, stream>>>(Wkr, rn1_g, rn1_b, bkr, Wvr, rn2_g, rn2_b, bvr,
                                        wcat1, wcat1 + 512 * 512, G1, B1, G2, B2);
  text_T<<<dim3(kB * kR, 8), 256, 0, stream>>>(re_text, rn1_g, Wkr, Tbuf);

  rowmask_kernel<<<dim3(kB * 4), 256, 0, stream>>>(cond, src_mask, re_mask,
      kaT_full, kaR_full, kaM_full, vmT_full, vmR_full, vmM_full, kB);
  silu_emb<<<dim3(kB * 2048 / 1024), 256, 0, stream>>>(emb, semb_f);
  emb_gemv2<<<dim3(256, 8), 256, 0, stream>>>(semb_f, emb_W, part_emb);
  emb_fin<<<dim3(128), 256, 0, stream>>>(part_emb, emb_b, ssb_full);

  for (int b0 = 0; b0 < kB; b0 += CH) {
    off = fixed_off;
    const int MRc = CH * 1024;
    const int MTc = CH * kNT;

    size_t xnr = pad((size_t)MRc * 512 * 2);
    if (att_bytes(CH) > xnr) xnr = att_bytes(CH);
    char* xnR = ab(xnr);
    unsigned short* xn_bf  = (unsigned short*)xnR;
    unsigned short* attT = (unsigned short*)xnR;
    float* attp = (float*)(xnR + pad((size_t)CH * 8 * 4096 * 2));
    float* part_cs = (float*)(xnR + pad((size_t)CH * 8 * 4096 * 2)
                                  + pad((size_t)CH * 8 * (size_t)kNS2 * 4096 * 4));
    unsigned short* h_bf = xn_bf;

    unsigned short* xfn_bf = (unsigned short*)ab((size_t)MTc * 256 * 2);
    unsigned short* mot_bf = (unsigned short*)ab((size_t)MRc * 512 * 2);
    float* s1k = (float*)ab((size_t)CH * 1024 * 4);
    float* s2k = (float*)ab((size_t)CH * 1024 * 4);
    float* s1v = (float*)ab((size_t)CH * 1024 * 4);
    float* s2v = (float*)ab((size_t)CH * 1024 * 4);
    unsigned short* qb_bf  = (unsigned short*)ab((size_t)MRc * 512 * 2);
    unsigned short* kc_bf  = (unsigned short*)ab((size_t)CH * 512 * kNtot * 2);
    unsigned short* vb_bf  = (unsigned short*)ab((size_t)CH * 512 * kNtot * 2);
    unsigned short* yb16 = mot_bf;

    const float* x_c   = x + (size_t)b0 * kT * 512;
    const float* xf_c  = xf + (size_t)b0 * kNT * 256;
    const float* rm_c  = re_motion + (size_t)b0 * kRL * 512;
    const float* rt_c  = re_text + (size_t)b0 * kR * 512;
    float* out_c = out + (size_t)b0 * kT * 512;

    // --- preprocessing ---
    ln_bf16<512><<<dim3(MRc), 256, 0, stream>>>(x_c, norm_g, norm_b, xn_bf);
    ln_bf16<256><<<dim3(MTc), 256, 0, stream>>>(xf_c, tnorm_g, tnorm_b, xfn_bf);
    rfk_stats<<<dim3(MRc), 256, 0, stream>>>(rm_c, rt_c, mot_bf, s1k, s2k, s1v, s2v);
    zpad_kernel<<<dim3(CH * 48), 256, 0, stream>>>(kc_bf, vb_bf, CH * 512);

    // --- fused projections (shared A, XCD-swizzled 1D grids, 3-buffer pipelined) ---
    gemm_fused<0, 12><<<dim3(12 * CH * 8), 256, 0, stream>>>(
        xn_bf, wcat0, MRc, 512, kT, kNT + kRL,
        qb_bf, kc_bf, vb_bf, bq, bkm, bvm,
        kaM_full + (size_t)b0 * kT, vmM_full + (size_t)b0 * kT,
        nullptr, nullptr, nullptr, nullptr, nullptr, nullptr, nullptr);
    gemm_fused<1, 8><<<dim3(8 * CH * 8), 256, 0, stream>>>(
        mot_bf, wcat1, MRc, 512, kRL, kNT,
        nullptr, kc_bf, vb_bf, B1, B2, nullptr,
        kaR_full + (size_t)b0 * kRL, vmR_full + (size_t)b0 * kRL,
        s1k, s2k, s1v, s2v, G1, G2, Tbuf + (size_t)b0 * kR * 512);
    gemm_fused<2, 8><<<dim3(8 * ((MTc + 127) / 128)), 256, 0, stream>>>(
        xfn_bf, wcat2, MTc, 256, kNT, 0,
        nullptr, kc_bf, vb_bf, bkt, bvt, nullptr,
        kaT_full + (size_t)b0 * kNT, vmT_full + (size_t)b0 * kNT,
        nullptr, nullptr, nullptr, nullptr, nullptr, nullptr, nullptr);

    // --- attention ---
    attp_kernel<<<dim3(CH * 8, kNS2), 256, 0, stream>>>(kc_bf, vb_bf, attp, part_cs);
    attc_kernel<<<dim3(CH * 8), 256, 0, stream>>>(attp, part_cs, attT);
    y_mfma<<<dim3(CH * 8, 8), 256, 0, stream>>>(qb_bf, attT, yb16);

    // --- modulation + output projection with fused residual ---
    mod_kernel<<<dim3(MRc), 256, 0, stream>>>(yb16, ssb_full + (size_t)b0 * 1024,
                                              snorm_g, snorm_b, h_bf);
    gemm_mfma<<<dim3(4 * CH * 8), 256, 0, stream>>>(h_bf, wout_bf, out_b,
                                                    x_c, out_c, MRc, 512);
  }
}

// Round 27
// 501.782 us; speedup vs baseline: 1.0837x; 1.0044x over previous
//
#include <hip/hip_runtime.h>
#include <cstddef>
#include <cstdint>

#define DEV __device__ __forceinline__

namespace {

constexpr int kH = 8;
constexpr int kB = 32, kT = 1024, kNT = 77, kR = 4, kLR = 256;
constexpr int kRL = kR * kLR;            // 1024
constexpr float kNEG = -1000000.0f;
constexpr int kNtot = 2304;              // padded n per (b,h,d) row (3*768)
constexpr int kNS2 = 3;                  // attention slices of 768 n

typedef __bf16 bf16x8 __attribute__((ext_vector_type(8)));
typedef float f32x4 __attribute__((ext_vector_type(4)));

DEV unsigned short f2bf(float f) {
  unsigned int u = __float_as_uint(f);
  u += 0x7fffu + ((u >> 16) & 1u);
  return (unsigned short)(u >> 16);
}
DEV float bf2f(unsigned short h) { return __uint_as_float(((unsigned int)h) << 16); }

DEV float wave_sum(float v) {
  #pragma unroll
  for (int s = 32; s; s >>= 1) v += __shfl_xor(v, s);
  return v;
}

// XCD-aware bijective swizzle (T1): contiguous grid chunk per XCD.
DEV int xcd_swz(int bid, int nwg) {
  if ((nwg & 7) == 0) return (bid & 7) * (nwg >> 3) + (bid >> 3);
  return bid;
}

// ---------------- LayerNorm -> bf16 ----------------
template<int COLS>
__global__ __launch_bounds__(256) void ln_bf16(const float* __restrict__ in,
    const float* __restrict__ g, const float* __restrict__ be,
    unsigned short* __restrict__ out) {
  constexpr int PT = COLS / 256;
  int row = blockIdx.x;
  const float* p = in + (size_t)row * COLS;
  unsigned short* o = out + (size_t)row * COLS;
  float v[PT]; float s = 0.f, s2 = 0.f;
  #pragma unroll
  for (int i = 0; i < PT; i++) {
    v[i] = p[threadIdx.x + i * 256];
    s += v[i]; s2 += v[i] * v[i];
  }
  __shared__ float red[2][4];
  int lane = threadIdx.x & 63, w = threadIdx.x >> 6;
  s = wave_sum(s); s2 = wave_sum(s2);
  if (!lane) { red[0][w] = s; red[1][w] = s2; }
  __syncthreads();
  s = red[0][0] + red[0][1] + red[0][2] + red[0][3];
  s2 = red[1][0] + red[1][1] + red[1][2] + red[1][3];
  float mean = s / COLS;
  float var = s2 / COLS - mean * mean;
  float rstd = rsqrtf(var + 1e-5f);
  #pragma unroll
  for (int i = 0; i < PT; i++) {
    int c = threadIdx.x + i * 256;
    o[c] = f2bf((v[i] - mean) * rstd * g[c] + be[c]);
  }
}

// ---- retrieval stats: mean/rstd scalars + motion cast ----
__global__ __launch_bounds__(256) void rfk_stats(const float* __restrict__ mot,
    const float* __restrict__ txt, unsigned short* __restrict__ mot_bf,
    float* __restrict__ s1k, float* __restrict__ s2k,
    float* __restrict__ s1v, float* __restrict__ s2v) {
  int m = blockIdx.x;
  const float* pm = mot + (size_t)m * 512;
  const float* pt = txt + (size_t)(m >> 8) * 512;
  float v[2], t[2];
  float sv = 0.f, sv2 = 0.f, st = 0.f, st2 = 0.f;
  #pragma unroll
  for (int i = 0; i < 2; i++) {
    v[i] = pm[threadIdx.x + i * 256]; sv += v[i]; sv2 += v[i] * v[i];
    t[i] = pt[threadIdx.x + i * 256]; st += t[i]; st2 += t[i] * t[i];
  }
  __shared__ float red[4][4];
  int lane = threadIdx.x & 63, w = threadIdx.x >> 6;
  sv = wave_sum(sv); sv2 = wave_sum(sv2); st = wave_sum(st); st2 = wave_sum(st2);
  if (!lane) { red[0][w] = sv; red[1][w] = sv2; red[2][w] = st; red[3][w] = st2; }
  __syncthreads();
  #pragma unroll
  for (int i = 0; i < 2; i++)
    mot_bf[(size_t)m * 512 + threadIdx.x + i * 256] = f2bf(v[i]);
  if (threadIdx.x == 0) {
    float SV = red[0][0] + red[0][1] + red[0][2] + red[0][3];
    float SV2 = red[1][0] + red[1][1] + red[1][2] + red[1][3];
    float ST = red[2][0] + red[2][1] + red[2][2] + red[2][3];
    float ST2 = red[3][0] + red[3][1] + red[3][2] + red[3][3];
    float SA = SV + ST, SA2 = SV2 + ST2;
    float ma = SA / 1024.f, va = SA2 / 1024.f - ma * ma;
    float ra = rsqrtf(va + 1e-5f);
    float mv = SV / 512.f, vv = SV2 / 512.f - mv * mv;
    float rv = rsqrtf(vv + 1e-5f);
    s1k[m] = ra; s2k[m] = -ra * ma;
    s1v[m] = rv; s2v[m] = -rv * mv;
  }
}

// ---- fold LN gains into retrieval weights (into wcat1 halves); per-col constants ----
__global__ __launch_bounds__(256) void prep_w(
    const float* __restrict__ Wkr, const float* __restrict__ g1,
    const float* __restrict__ b1, const float* __restrict__ bkr,
    const float* __restrict__ Wvr, const float* __restrict__ g2,
    const float* __restrict__ b2, const float* __restrict__ bvr,
    unsigned short* __restrict__ w1lo, unsigned short* __restrict__ w2,
    float* __restrict__ G1, float* __restrict__ B1,
    float* __restrict__ G2, float* __restrict__ B2) {
  int n = blockIdx.x;   // 512
  int tid = threadIdx.x;
  float gs = 0.f, bs = 0.f;
  #pragma unroll
  for (int i = 0; i < 4; i++) {
    int k = tid + i * 256;
    float w = Wkr[(size_t)n * 1024 + k];
    float gv = g1[k];
    gs += gv * w; bs += b1[k] * w;
    if (i < 2) w1lo[(size_t)n * 512 + k] = f2bf(gv * w);
  }
  float g2s = 0.f, b2s = 0.f;
  #pragma unroll
  for (int i = 0; i < 2; i++) {
    int k = tid + i * 256;
    float w = Wvr[(size_t)n * 512 + k];
    g2s += g2[k] * w; b2s += b2[k] * w;
    w2[(size_t)n * 512 + k] = f2bf(g2[k] * w);
  }
  __shared__ float red[4][4];
  int lane = tid & 63, w_ = tid >> 6;
  gs = wave_sum(gs); bs = wave_sum(bs); g2s = wave_sum(g2s); b2s = wave_sum(b2s);
  if (!lane) { red[0][w_] = gs; red[1][w_] = bs; red[2][w_] = g2s; red[3][w_] = b2s; }
  __syncthreads();
  if (tid == 0) {
    G1[n] = red[0][0] + red[0][1] + red[0][2] + red[0][3];
    B1[n] = red[1][0] + red[1][1] + red[1][2] + red[1][3] + bkr[n];
    G2[n] = red[2][0] + red[2][1] + red[2][2] + red[2][3];
    B2[n] = red[3][0] + red[3][1] + red[3][2] + red[3][3] + bvr[n];
  }
}

// ---- T[m][n] = (g1_hi * text[m]) . Wkr[n, 512:1024] ; grid (128 m, 8 n-slices) ----
__global__ __launch_bounds__(256) void text_T(const float* __restrict__ re_text,
    const float* __restrict__ g1, const float* __restrict__ Wkr,
    float* __restrict__ T) {
  int m = blockIdx.x;
  int ns = blockIdx.y;
  __shared__ float tr[512];
  int tid = threadIdx.x;
  #pragma unroll
  for (int i = 0; i < 2; i++) {
    int k = tid + i * 256;
    tr[k] = re_text[(size_t)m * 512 + k] * g1[512 + k];
  }
  __syncthreads();
  int n = ns * 64 + (tid >> 2);
  int k0 = (tid & 3) * 128;
  const float* wp = Wkr + (size_t)n * 1024 + 512 + k0;
  float acc = 0.f;
  #pragma unroll
  for (int k = 0; k < 128; k += 4) {
    float4 w4 = *reinterpret_cast<const float4*>(wp + k);
    float4 t4 = *reinterpret_cast<const float4*>(&tr[k0 + k]);
    acc = fmaf(t4.x, w4.x, fmaf(t4.y, w4.y, fmaf(t4.z, w4.z, fmaf(t4.w, w4.w, acc))));
  }
  acc += __shfl_xor(acc, 1);
  acc += __shfl_xor(acc, 2);
  if ((tid & 3) == 0) T[(size_t)m * 512 + n] = acc;
}

// ---------------- per-row mask arrays (full batch) ----------------
__global__ __launch_bounds__(256) void rowmask_kernel(const int* __restrict__ ct,
    const float* __restrict__ src_mask, const float* __restrict__ re_mask,
    float* __restrict__ kaT, float* __restrict__ kaR, float* __restrict__ kaM,
    float* __restrict__ vmT, float* __restrict__ vmR, float* __restrict__ vmM,
    int nB) {
  int i = blockIdx.x * 256 + threadIdx.x;
  if (i < nB * kRL) {
    int b = i >> 10;
    int c = ct[b];
    float retr = (c / 10 > 0) ? 1.f : 0.f;
    float rm = re_mask[i];
    kaR[i] = (1.f - retr) * kNEG + (1.f - rm) * kNEG;
    vmR[i] = retr * rm;
    float sm = src_mask[i];
    kaM[i] = (1.f - sm) * kNEG;
    vmM[i] = sm;
  }
  if (i < nB * kNT) {
    int b = i / kNT;
    int c = ct[b];
    float text = (c % 10 > 0) ? 1.f : 0.f;
    kaT[i] = (1.f - text) * kNEG;
    vmT[i] = text;
  }
}

// ---------------- weight cast f32 -> bf16 ----------------
__global__ __launch_bounds__(256) void castw(const float* __restrict__ s,
    unsigned short* __restrict__ d, int n) {
  int i = (blockIdx.x * 256 + threadIdx.x) * 4;
  if (i < n) {
    float4 v = *reinterpret_cast<const float4*>(s + i);
    ushort4 o;
    o.x = f2bf(v.x); o.y = f2bf(v.y); o.z = f2bf(v.z); o.w = f2bf(v.w);
    *reinterpret_cast<ushort4*>(d + i) = o;
  }
}

// ---------------- zero-pad tail of E'/V' rows ----------------
__global__ __launch_bounds__(256) void zpad_kernel(unsigned short* __restrict__ E,
    unsigned short* __restrict__ V, int rows) {
  int i = blockIdx.x * 256 + threadIdx.x;
  if (i >= rows * 24) return;
  int row = i / 24, c = i % 24;
  size_t off = (size_t)row * kNtot + 2112 + c * 8;
  ulonglong2 z; z.x = 0; z.y = 0;
  *reinterpret_cast<ulonglong2*>(E + off) = z;
  *reinterpret_cast<ulonglong2*>(V + off) = z;
}

// ---------------- silu(emb) precompute (f32) ----------------
__global__ __launch_bounds__(256) void silu_emb(const float* __restrict__ emb,
    float* __restrict__ semb) {
  int i = (blockIdx.x * 256 + threadIdx.x) * 4;
  float4 v = *reinterpret_cast<const float4*>(emb + i);
  float4 o;
  o.x = v.x / (1.f + __expf(-v.x));
  o.y = v.y / (1.f + __expf(-v.y));
  o.z = v.z / (1.f + __expf(-v.z));
  o.w = v.w / (1.f + __expf(-v.w));
  *reinterpret_cast<float4*>(semb + i) = o;
}

// ---------------- emb GEMV split-K ----------------
__global__ __launch_bounds__(256) void emb_gemv2(const float* __restrict__ semb,
    const float* __restrict__ W, float* __restrict__ part) {
  int n = blockIdx.x * 4 + (threadIdx.x >> 6);
  int s = blockIdx.y;
  int lane = threadIdx.x & 63;
  int k = s * 256 + lane * 4;
  float4 wv = *reinterpret_cast<const float4*>(&W[(size_t)n * 2048 + k]);
  float acc[32];
  #pragma unroll
  for (int m = 0; m < 32; m++) {
    float4 sv = *reinterpret_cast<const float4*>(&semb[(size_t)m * 2048 + k]);
    acc[m] = fmaf(sv.x, wv.x, fmaf(sv.y, wv.y, fmaf(sv.z, wv.z, sv.w * wv.w)));
  }
  #pragma unroll
  for (int m = 0; m < 32; m++) {
    float t = wave_sum(acc[m]);
    if (lane == 0) part[((size_t)s * 32 + m) * 1024 + n] = t;
  }
}
__global__ __launch_bounds__(256) void emb_fin(const float* __restrict__ part,
    const float* __restrict__ bias, float* __restrict__ ss) {
  int i = blockIdx.x * 256 + threadIdx.x;
  float s = 0.f;
  #pragma unroll
  for (int c = 0; c < 8; c++) s += part[(size_t)c * 32768 + i];
  ss[i] = s + bias[i & 1023];
}

// ================= FUSED MFMA GEMM (shared-A, multi-W sections) =================
// 3-buffer pipelined K-loop with counted vmcnt; raw barriers (no drain).
// 1D grid, XCD-swizzled: wg = xcd_swz(bid); m-tile = wg / NX, n-tile = wg % NX.
template<int COMBO, int NX>
__global__ __launch_bounds__(256) void gemm_fused(
    const unsigned short* __restrict__ A, const unsigned short* __restrict__ W,
    int M, int K, int m_per_b, int out_off,
    unsigned short* __restrict__ qout,
    unsigned short* __restrict__ E, unsigned short* __restrict__ V,
    const float* __restrict__ biasA, const float* __restrict__ biasB,
    const float* __restrict__ biasC,
    const float* __restrict__ rowAddK, const float* __restrict__ rowMulV,
    const float* __restrict__ s1k, const float* __restrict__ s2k,
    const float* __restrict__ s1v, const float* __restrict__ s2v,
    const float* __restrict__ G1v, const float* __restrict__ G2v,
    const float* __restrict__ Tt) {
  __shared__ __align__(16) char smem[49152];   // 3x16KB staging | 32KB epilogue
  unsigned short* lds = (unsigned short*)smem;
  const int tid = threadIdx.x;
  const int lane = tid & 63;
  const int wv = tid >> 6;
  const int wr = (wv >> 1) * 64;
  const int wc = (wv & 1) * 64;
  const int wg = xcd_swz(blockIdx.x, gridDim.x);
  const int m0 = (wg / NX) * 128;
  const int n0 = (wg % NX) * 128;
  const int sec = n0 >> 9;
  const int nlo = n0 & 511;

  const unsigned short* srcA[2]; const unsigned short* srcB[2];
  int dstOff[2];
  #pragma unroll
  for (int i = 0; i < 2; i++) {
    int lin = i * 256 + tid;
    int r = lin >> 2, cl = lin & 3;
    int cs = cl ^ ((r >> 1) & 3);
    int ra = m0 + r; if (ra > M - 1) ra = M - 1;
    srcA[i] = A + (size_t)ra * K + cs * 8;
    srcB[i] = W + (size_t)(n0 + r) * K + cs * 8;
    dstOff[i] = lin * 8;
  }
  int offA[4], offB[4];
  #pragma unroll
  for (int i = 0; i < 4; i++) {
    int r = wr + i * 16 + (lane & 15);
    int c = (lane >> 4) ^ ((r >> 1) & 3);
    offA[i] = r * 32 + c * 8;
    int rb = wc + i * 16 + (lane & 15);
    int cb = (lane >> 4) ^ ((rb >> 1) & 3);
    offB[i] = rb * 32 + cb * 8;
  }

  f32x4 acc[4][4] = {};
  const int nt = K >> 5;

  #pragma unroll
  for (int i = 0; i < 2; i++) {
    __builtin_amdgcn_global_load_lds(
        (const __attribute__((address_space(1))) void*)(srcA[i]),
        (__attribute__((address_space(3))) void*)&lds[dstOff[i]], 16, 0, 0);
    __builtin_amdgcn_global_load_lds(
        (const __attribute__((address_space(1))) void*)(srcB[i]),
        (__attribute__((address_space(3))) void*)&lds[4096 + dstOff[i]], 16, 0, 0);
  }

  int cur = 0;
  for (int t = 0; t < nt; t++) {
    int nxt = cur + 1; if (nxt == 3) nxt = 0;
    if (t + 1 < nt) {
      int ko = (t + 1) << 5;
      #pragma unroll
      for (int i = 0; i < 2; i++) {
        __builtin_amdgcn_global_load_lds(
            (const __attribute__((address_space(1))) void*)(srcA[i] + ko),
            (__attribute__((address_space(3))) void*)&lds[nxt * 8192 + dstOff[i]], 16, 0, 0);
        __builtin_amdgcn_global_load_lds(
            (const __attribute__((address_space(1))) void*)(srcB[i] + ko),
            (__attribute__((address_space(3))) void*)&lds[nxt * 8192 + 4096 + dstOff[i]], 16, 0, 0);
      }
      asm volatile("s_waitcnt vmcnt(4)" ::: "memory");
    } else {
      asm volatile("s_waitcnt vmcnt(0)" ::: "memory");
    }
    __builtin_amdgcn_s_barrier();
    __builtin_amdgcn_sched_barrier(0);
    bf16x8 af[4], bf[4];
    #pragma unroll
    for (int i = 0; i < 4; i++) {
      af[i] = *reinterpret_cast<const bf16x8*>(&lds[cur * 8192 + offA[i]]);
      bf[i] = *reinterpret_cast<const bf16x8*>(&lds[cur * 8192 + 4096 + offB[i]]);
    }
    #pragma unroll
    for (int i = 0; i < 4; i++)
      #pragma unroll
      for (int j = 0; j < 4; j++)
        acc[i][j] = __builtin_amdgcn_mfma_f32_16x16x32_bf16(af[i], bf[j], acc[i][j], 0, 0, 0);
    cur = nxt;
  }
  __syncthreads();   // all loads done; sync before epilogue reuses LDS

  const int r4 = (lane >> 4) << 2;
  const int rowb = m0 + wr + r4;

  auto epival = [&](float accv, int rowg, int cl) -> float {
    if (COMBO == 0) {
      if (sec == 0) return __expf(accv + biasA[cl]);
      if (sec == 1) return __expf(accv + biasB[cl] + rowAddK[rowg]);
      return (accv + biasC[cl]) * rowMulV[rowg];
    } else if (COMBO == 1) {
      if (sec == 0)
        return __expf((accv + Tt[(size_t)(rowg >> 8) * 512 + cl]) * s1k[rowg]
                      + s2k[rowg] * G1v[cl] + biasA[cl] + rowAddK[rowg]);
      return (accv * s1v[rowg] + s2v[rowg] * G2v[cl] + biasB[cl]) * rowMulV[rowg];
    } else {
      if (sec == 0) return __expf(accv + biasA[cl] + rowAddK[rowg]);
      return (accv + biasB[cl]) * rowMulV[rowg];
    }
  };

  unsigned short* dstEV = (COMBO == 0) ? (sec == 1 ? E : V) : (sec == 0 ? E : V);

  if (COMBO == 2) {
    // scalar transposed epilogue (m_per_b = 77)
    #pragma unroll
    for (int i = 0; i < 4; i++) {
      #pragma unroll
      for (int r = 0; r < 4; r++) {
        int row = rowb + i * 16 + r;
        if (row >= M) continue;
        size_t nn = out_off + (row % m_per_b);
        size_t cb = (size_t)(row / m_per_b) * 512;
        #pragma unroll
        for (int j = 0; j < 4; j++) {
          int cl = nlo + wc + j * 16 + (lane & 15);
          dstEV[(cb + cl) * kNtot + nn] = f2bf(epival(acc[i][j][r], row, cl));
        }
      }
    }
    return;
  }

  // staged epilogue [128][128] bf16, XOR-keyed
  unsigned short* S = (unsigned short*)smem;
  #pragma unroll
  for (int i = 0; i < 4; i++) {
    #pragma unroll
    for (int r = 0; r < 4; r++) {
      int row_t = wr + i * 16 + r4 + r;
      int rowg = m0 + row_t; if (rowg > M - 1) rowg = M - 1;
      int key = ((row_t >> 3) & 7) << 3;
      #pragma unroll
      for (int j = 0; j < 4; j++) {
        int col_t = wc + j * 16 + (lane & 15);
        S[row_t * 128 + (col_t ^ key)] = f2bf(epival(acc[i][j][r], rowg, nlo + col_t));
      }
    }
  }
  __syncthreads();
  bool linear = (COMBO == 0 && sec == 0);
  if (linear) {
    #pragma unroll
    for (int it = 0; it < 8; it++) {
      int slot = it * 256 + tid;
      int row_t = slot >> 4;
      int cs = (slot & 15) * 8;
      int key = ((row_t >> 3) & 7) << 3;
      int row = m0 + row_t;
      if (row < M) {
        ulonglong2 d = *reinterpret_cast<const ulonglong2*>(&S[row_t * 128 + (cs ^ key)]);
        *reinterpret_cast<ulonglong2*>(qout + (size_t)row * 512 + nlo + cs) = d;
      }
    }
  } else {
    #pragma unroll
    for (int it = 0; it < 8; it++) {
      int slot = it * 256 + tid;
      int col_t = slot >> 4;
      int mcx = slot & 15;
      int mc = mcx * 8;
      int key = (mcx & 7) << 3;
      union { unsigned short u[8]; ulonglong2 v; } w;
      #pragma unroll
      for (int e = 0; e < 8; e++)
        w.u[e] = S[(mc + e) * 128 + (col_t ^ key)];
      int row = m0 + mc;   // M % 128 == 0 here
      size_t obase = ((size_t)(row / m_per_b) * 512 + nlo + col_t) * (size_t)kNtot
                   + out_off + (row % m_per_b);
      *reinterpret_cast<ulonglong2*>(dstEV + obase) = w.v;
    }
  }
}

// ------- plain MFMA GEMM (final projection) + fused residual: out = x + (C+bias) -------
__global__ __launch_bounds__(256) void gemm_mfma(
    const unsigned short* __restrict__ A, const unsigned short* __restrict__ W,
    const float* __restrict__ bias, const float* __restrict__ Xres,
    float* __restrict__ Outf, int M, int K) {
  __shared__ __align__(16) char smem[49152];
  unsigned short* lds = (unsigned short*)smem;
  const int tid = threadIdx.x;
  const int lane = tid & 63;
  const int wv = tid >> 6;
  const int wr = (wv >> 1) * 64;
  const int wc = (wv & 1) * 64;
  const int wg = xcd_swz(blockIdx.x, gridDim.x);
  const int m0 = (wg >> 2) * 128;
  const int n0 = (wg & 3) * 128;

  const unsigned short* srcA[2]; const unsigned short* srcB[2];
  int dstOff[2];
  #pragma unroll
  for (int i = 0; i < 2; i++) {
    int lin = i * 256 + tid;
    int r = lin >> 2, cl = lin & 3;
    int cs = cl ^ ((r >> 1) & 3);
    int ra = m0 + r; if (ra > M - 1) ra = M - 1;
    srcA[i] = A + (size_t)ra * K + cs * 8;
    srcB[i] = W + (size_t)(n0 + r) * K + cs * 8;
    dstOff[i] = lin * 8;
  }
  int offA[4], offB[4];
  #pragma unroll
  for (int i = 0; i < 4; i++) {
    int r = wr + i * 16 + (lane & 15);
    int c = (lane >> 4) ^ ((r >> 1) & 3);
    offA[i] = r * 32 + c * 8;
    int rb = wc + i * 16 + (lane & 15);
    int cb = (lane >> 4) ^ ((rb >> 1) & 3);
    offB[i] = rb * 32 + cb * 8;
  }

  f32x4 acc[4][4] = {};
  const int nt = K >> 5;

  #pragma unroll
  for (int i = 0; i < 2; i++) {
    __builtin_amdgcn_global_load_lds(
        (const __attribute__((address_space(1))) void*)(srcA[i]),
        (__attribute__((address_space(3))) void*)&lds[dstOff[i]], 16, 0, 0);
    __builtin_amdgcn_global_load_lds(
        (const __attribute__((address_space(1))) void*)(srcB[i]),
        (__attribute__((address_space(3))) void*)&lds[4096 + dstOff[i]], 16, 0, 0);
  }

  int cur = 0;
  for (int t = 0; t < nt; t++) {
    int nxt = cur + 1; if (nxt == 3) nxt = 0;
    if (t + 1 < nt) {
      int ko = (t + 1) << 5;
      #pragma unroll
      for (int i = 0; i < 2; i++) {
        __builtin_amdgcn_global_load_lds(
            (const __attribute__((address_space(1))) void*)(srcA[i] + ko),
            (__attribute__((address_space(3))) void*)&lds[nxt * 8192 + dstOff[i]], 16, 0, 0);
        __builtin_amdgcn_global_load_lds(
            (const __attribute__((address_space(1))) void*)(srcB[i] + ko),
            (__attribute__((address_space(3))) void*)&lds[nxt * 8192 + 4096 + dstOff[i]], 16, 0, 0);
      }
      asm volatile("s_waitcnt vmcnt(4)" ::: "memory");
    } else {
      asm volatile("s_waitcnt vmcnt(0)" ::: "memory");
    }
    __builtin_amdgcn_s_barrier();
    __builtin_amdgcn_sched_barrier(0);
    bf16x8 af[4], bf[4];
    #pragma unroll
    for (int i = 0; i < 4; i++) {
      af[i] = *reinterpret_cast<const bf16x8*>(&lds[cur * 8192 + offA[i]]);
      bf[i] = *reinterpret_cast<const bf16x8*>(&lds[cur * 8192 + 4096 + offB[i]]);
    }
    #pragma unroll
    for (int i = 0; i < 4; i++)
      #pragma unroll
      for (int j = 0; j < 4; j++)
        acc[i][j] = __builtin_amdgcn_mfma_f32_16x16x32_bf16(af[i], bf[j], acc[i][j], 0, 0, 0);
    cur = nxt;
  }
  __syncthreads();

  const int r4 = (lane >> 4) << 2;
  unsigned short* S = (unsigned short*)smem;
  #pragma unroll
  for (int i = 0; i < 4; i++) {
    #pragma unroll
    for (int r = 0; r < 4; r++) {
      int row_t = wr + i * 16 + r4 + r;
      int key = ((row_t >> 3) & 7) << 3;
      #pragma unroll
      for (int j = 0; j < 4; j++) {
        int col_t = wc + j * 16 + (lane & 15);
        S[row_t * 128 + (col_t ^ key)] = f2bf(acc[i][j][r] + bias[n0 + col_t]);
      }
    }
  }
  __syncthreads();
  #pragma unroll
  for (int it = 0; it < 8; it++) {
    int slot = it * 256 + tid;
    int row_t = slot >> 4;
    int cs = (slot & 15) * 8;
    int key = ((row_t >> 3) & 7) << 3;
    int row = m0 + row_t;
    if (row < M) {
      union { unsigned short u[8]; ulonglong2 v; } w;
      w.v = *reinterpret_cast<const ulonglong2*>(&S[row_t * 128 + (cs ^ key)]);
      const float* xp = Xres + (size_t)row * 512 + n0 + cs;
      float4 x0 = *reinterpret_cast<const float4*>(xp);
      float4 x1 = *reinterpret_cast<const float4*>(xp + 4);
      float4 o0, o1;
      o0.x = x0.x + bf2f(w.u[0]); o0.y = x0.y + bf2f(w.u[1]);
      o0.z = x0.z + bf2f(w.u[2]); o0.w = x0.w + bf2f(w.u[3]);
      o1.x = x1.x + bf2f(w.u[4]); o1.y = x1.y + bf2f(w.u[5]);
      o1.z = x1.z + bf2f(w.u[6]); o1.w = x1.w + bf2f(w.u[7]);
      float* op = Outf + (size_t)row * 512 + n0 + cs;
      *reinterpret_cast<float4*>(op) = o0;
      *reinterpret_cast<float4*>(op + 4) = o1;
    }
  }
}

// ---- attention partials via MFMA (NT form), wave-per-d-slab ----
__global__ __launch_bounds__(256) void attp_kernel(const unsigned short* __restrict__ E,
    const unsigned short* __restrict__ V, float* __restrict__ part,
    float* __restrict__ part_cs) {
  int bh = blockIdx.x;
  int s = blockIdx.y;
  const unsigned short* Ep = E + (size_t)bh * 64 * kNtot;
  const unsigned short* Vp = V + (size_t)bh * 64 * kNtot;
  __shared__ __align__(16) char smem[34816];
  unsigned short* Elds = (unsigned short*)smem;             // [64][136]
  unsigned short* Vlds = (unsigned short*)(smem + 17408);
  int tid = threadIdx.x, lane = tid & 63, wv = tid >> 6;
  f32x4 acc[4] = {};
  float csum = 0.f;
  int cd = tid & 63, cq = tid >> 6;
  const int arow = (wv * 16 + (lane & 15)) * 136 + ((lane >> 4) << 3);
  const int brow0 = ((lane & 15)) * 136 + ((lane >> 4) << 3);

  for (int it = 0; it < 6; it++) {
    int n0 = s * 768 + it * 128;
    __syncthreads();
    #pragma unroll
    for (int r = 0; r < 4; r++) {
      int ch = r * 256 + tid;
      int d = ch >> 4, off = (ch & 15) * 8;
      *reinterpret_cast<ulonglong2*>(&Elds[d * 136 + off]) =
          *reinterpret_cast<const ulonglong2*>(Ep + (size_t)d * kNtot + n0 + off);
      *reinterpret_cast<ulonglong2*>(&Vlds[d * 136 + off]) =
          *reinterpret_cast<const ulonglong2*>(Vp + (size_t)d * kNtot + n0 + off);
    }
    __syncthreads();
    #pragma unroll
    for (int ks = 0; ks < 4; ks++) {
      bf16x8 af = *reinterpret_cast<const bf16x8*>(&Elds[arow + ks * 32]);
      #pragma unroll
      for (int j = 0; j < 4; j++) {
        bf16x8 bf = *reinterpret_cast<const bf16x8*>(&Vlds[brow0 + j * 16 * 136 + ks * 32]);
        acc[j] = __builtin_amdgcn_mfma_f32_16x16x32_bf16(af, bf, acc[j], 0, 0, 0);
      }
    }
    #pragma unroll
    for (int k8 = 0; k8 < 4; k8++) {
      bf16x8 ev = *reinterpret_cast<const bf16x8*>(&Elds[cd * 136 + cq * 32 + k8 * 8]);
      const unsigned short* pu = reinterpret_cast<const unsigned short*>(&ev);
      #pragma unroll
      for (int e = 0; e < 8; e++) csum += bf2f(pu[e]);
    }
  }
  float* op = part + ((size_t)bh * kNS2 + s) * 4096;
  int dbase = wv * 16 + ((lane >> 4) << 2);
  #pragma unroll
  for (int j = 0; j < 4; j++)
    #pragma unroll
    for (int r = 0; r < 4; r++)
      op[(dbase + r) * 64 + j * 16 + (lane & 15)] = acc[j][r];
  __syncthreads();
  float* csu = (float*)smem;
  csu[cq * 64 + cd] = csum;
  __syncthreads();
  if (tid < 64)
    part_cs[((size_t)bh * kNS2 + s) * 64 + tid] =
        csu[tid] + csu[64 + tid] + csu[128 + tid] + csu[192 + tid];
}

// ---- combine partials, apply 1/colsum, write att^T bf16 [l][d] ----
__global__ __launch_bounds__(256) void attc_kernel(const float* __restrict__ part,
    const float* __restrict__ part_cs, unsigned short* __restrict__ attT) {
  int bh = blockIdx.x;
  __shared__ float at[64][65];
  __shared__ float sinv[64];
  int tid = threadIdx.x;
  if (tid < 64) {
    float s = 0.f;
    #pragma unroll
    for (int c = 0; c < kNS2; c++) s += part_cs[((size_t)bh * kNS2 + c) * 64 + tid];
    sinv[tid] = 1.f / s;
  }
  for (int i = tid; i < 4096; i += 256) {
    float s = 0.f;
    #pragma unroll
    for (int c = 0; c < kNS2; c++) s += part[((size_t)bh * kNS2 + c) * 4096 + i];
    at[i >> 6][i & 63] = s;
  }
  __syncthreads();
  for (int j = tid; j < 4096; j += 256) {
    int l = j >> 6, d = j & 63;
    attT[(size_t)bh * 4096 + j] = f2bf(at[d][l] * sinv[d]);
  }
}

// ---- y = (expq/rowsum) @ att via MFMA; y bf16 ----
__global__ __launch_bounds__(256) void y_mfma(const unsigned short* __restrict__ q,
    const unsigned short* __restrict__ attT, unsigned short* __restrict__ y) {
  int bh = blockIdx.x; int b = bh >> 3, h = bh & 7;
  int t0 = blockIdx.y * 128;
  __shared__ unsigned short bt[64][72];
  __shared__ float rs[128];
  __shared__ unsigned short ob[128][72];
  int tid = threadIdx.x, lane = tid & 63, wv = tid >> 6;
  int wr = wv * 32;
  for (int i = tid; i < 512; i += 256) {
    int row = i >> 3, c8 = (i & 7) * 8;
    *reinterpret_cast<ulonglong2*>(&bt[row][c8]) =
        *reinterpret_cast<const ulonglong2*>(attT + (size_t)bh * 4096 + row * 64 + c8);
  }
  const unsigned short* qp = q + ((size_t)(b * 1024 + t0 + wr)) * 512 + h * 64;
  bf16x8 af[2][2];
  #pragma unroll
  for (int i = 0; i < 2; i++) {
    int row = i * 16 + (lane & 15);
    #pragma unroll
    for (int s = 0; s < 2; s++)
      af[i][s] = *reinterpret_cast<const bf16x8*>(qp + (size_t)row * 512 + s * 32 + (lane >> 4) * 8);
  }
  #pragma unroll
  for (int i = 0; i < 2; i++) {
    float r = 0.f;
    #pragma unroll
    for (int s = 0; s < 2; s++) {
      const unsigned short* pu = reinterpret_cast<const unsigned short*>(&af[i][s]);
      #pragma unroll
      for (int e = 0; e < 8; e++) r += bf2f(pu[e]);
    }
    r += __shfl_xor(r, 16); r += __shfl_xor(r, 32);
    if (lane < 16) rs[wr + i * 16 + lane] = r;
  }
  __syncthreads();
  f32x4 acc[2][4] = {};
  #pragma unroll
  for (int s = 0; s < 2; s++) {
    #pragma unroll
    for (int j = 0; j < 4; j++) {
      bf16x8 bf = *reinterpret_cast<const bf16x8*>(&bt[j * 16 + (lane & 15)][s * 32 + (lane >> 4) * 8]);
      #pragma unroll
      for (int i = 0; i < 2; i++)
        acc[i][j] = __builtin_amdgcn_mfma_f32_16x16x32_bf16(af[i][s], bf, acc[i][j], 0, 0, 0);
    }
  }
  int r4 = (lane >> 4) << 2;
  #pragma unroll
  for (int i = 0; i < 2; i++) {
    #pragma unroll
    for (int r = 0; r < 4; r++) {
      int row = wr + i * 16 + r4 + r;
      float rinv = 1.f / rs[row];
      #pragma unroll
      for (int j = 0; j < 4; j++)
        ob[row][j * 16 + (lane & 15)] = f2bf(acc[i][j][r] * rinv);
    }
  }
  __syncthreads();
  for (int i = tid; i < 1024; i += 256) {
    int row = i >> 3, c8 = (i & 7) * 8;
    *reinterpret_cast<ulonglong2*>(y + ((size_t)(b * 1024 + t0 + row)) * 512 + h * 64 + c8) =
        *reinterpret_cast<const ulonglong2*>(&ob[row][c8]);
  }
}

// ---------------- LN(y)*(1+scale)+shift then SiLU -> bf16 ----------------
__global__ __launch_bounds__(256) void mod_kernel(const unsigned short* __restrict__ y,
    const float* __restrict__ ss, const float* __restrict__ g, const float* __restrict__ be,
    unsigned short* __restrict__ h) {
  int row = blockIdx.x; int b = row >> 10;
  const unsigned short* p = y + (size_t)row * 512;
  unsigned short* o = h + (size_t)row * 512;
  float v[2]; float s = 0.f, s2 = 0.f;
  #pragma unroll
  for (int i = 0; i < 2; i++) {
    v[i] = bf2f(p[threadIdx.x + i * 256]);
    s += v[i]; s2 += v[i] * v[i];
  }
  __shared__ float red[2][4];
  int lane = threadIdx.x & 63, w = threadIdx.x >> 6;
  s = wave_sum(s); s2 = wave_sum(s2);
  if (!lane) { red[0][w] = s; red[1][w] = s2; }
  __syncthreads();
  s = red[0][0] + red[0][1] + red[0][2] + red[0][3];
  s2 = red[1][0] + red[1][1] + red[1][2] + red[1][3];
  float mean = s / 512.f, var = s2 / 512.f - mean * mean;
  float rstd = rsqrtf(var + 1e-5f);
  #pragma unroll
  for (int i = 0; i < 2; i++) {
    int c = threadIdx.x + i * 256;
    float val = (v[i] - mean) * rstd * g[c] + be[c];
    val = val * (1.f + ss[b * 1024 + c]) + ss[b * 1024 + 512 + c];
    o[c] = f2bf(val / (1.f + __expf(-val)));
  }
}

}  // namespace

extern "C" void kernel_launch(void* const* d_in, const int* in_sizes, int n_in,
                              void* d_out, int out_size, void* d_ws, size_t ws_size,
                              hipStream_t stream) {
  const float* x        = (const float*)d_in[0];
  const float* xf       = (const float*)d_in[1];
  const float* emb      = (const float*)d_in[2];
  const float* src_mask = (const float*)d_in[3];
  const int*   cond     = (const int*)d_in[4];
  const float* re_motion= (const float*)d_in[5];
  const float* re_text  = (const float*)d_in[6];
  const float* re_mask  = (const float*)d_in[7];
  const float* norm_g = (const float*)d_in[8],  * norm_b = (const float*)d_in[9];
  const float* tnorm_g= (const float*)d_in[10], * tnorm_b= (const float*)d_in[11];
  const float* rn1_g  = (const float*)d_in[12], * rn1_b  = (const float*)d_in[13];
  const float* rn2_g  = (const float*)d_in[14], * rn2_b  = (const float*)d_in[15];
  const float* Wq  = (const float*)d_in[16], * bq  = (const float*)d_in[17];
  const float* Wkt = (const float*)d_in[18], * bkt = (const float*)d_in[19];
  const float* Wvt = (const float*)d_in[20], * bvt = (const float*)d_in[21];
  const float* Wkm = (const float*)d_in[22], * bkm = (const float*)d_in[23];
  const float* Wvm = (const float*)d_in[24], * bvm = (const float*)d_in[25];
  const float* Wkr = (const float*)d_in[26], * bkr = (const float*)d_in[27];
  const float* Wvr = (const float*)d_in[28], * bvr = (const float*)d_in[29];
  const float* emb_W = (const float*)d_in[30], * emb_b = (const float*)d_in[31];
  const float* snorm_g = (const float*)d_in[32], * snorm_b = (const float*)d_in[33];
  const float* out_W = (const float*)d_in[34], * out_b = (const float*)d_in[35];
  float* out = (float*)d_out;

  char* base = (char*)d_ws;
  size_t off = 0;
  auto ab = [&](size_t nb) { char* p = base + off; off = (off + nb + 255) & ~(size_t)255; return p; };

  unsigned short* wcat0 = (unsigned short*)ab((size_t)1536 * 512 * 2);  // Wq|Wkm|Wvm
  unsigned short* wcat1 = (unsigned short*)ab((size_t)1024 * 512 * 2);  // W'kr|W'vr
  unsigned short* wcat2 = (unsigned short*)ab((size_t)1024 * 256 * 2);  // Wkt|Wvt
  unsigned short* wout_bf= (unsigned short*)ab(512 * 512 * 2);
  float* G1 = (float*)ab(512 * 4); float* B1 = (float*)ab(512 * 4);
  float* G2 = (float*)ab(512 * 4); float* B2 = (float*)ab(512 * 4);
  float* Tbuf = (float*)ab((size_t)kB * kR * 512 * 4);
  float* semb_f   = (float*)ab((size_t)kB * 2048 * 4);
  float* part_emb = (float*)ab((size_t)8 * kB * 1024 * 4);
  float* ssb_full = (float*)ab((size_t)kB * 1024 * 4);
  float* kaT_full = (float*)ab((size_t)kB * kNT * 4);
  float* vmT_full = (float*)ab((size_t)kB * kNT * 4);
  float* kaR_full = (float*)ab((size_t)kB * kRL * 4);
  float* kaM_full = (float*)ab((size_t)kB * kT * 4);
  float* vmR_full = (float*)ab((size_t)kB * kRL * 4);
  float* vmM_full = (float*)ab((size_t)kB * kT * 4);
  const size_t fixed_off = off;

  auto pad = [](size_t n) { return (n + 255) & ~(size_t)255; };
  auto att_bytes = [&](size_t CH) -> size_t {
    return pad(CH * 8 * 4096 * 2)
         + pad(CH * 8 * (size_t)kNS2 * 4096 * 4)
         + pad(CH * 8 * (size_t)kNS2 * 64 * 4);
  };
  auto chunk_bytes = [&](size_t CH) -> size_t {
    size_t xnr = pad(CH * 1024 * 512 * 2);
    if (att_bytes(CH) > xnr) xnr = att_bytes(CH);
    size_t s = 0;
    s += xnr;
    s += pad(CH * kNT * 256 * 2);
    s += pad(CH * 1024 * 512 * 2);
    s += 4 * pad(CH * 1024 * 4);
    s += pad(CH * 1024 * 512 * 2);
    s += pad((size_t)CH * 512 * kNtot * 2);
    s += pad((size_t)CH * 512 * kNtot * 2);
    return s;
  };
  int CH = 32;
  while (CH > 1 && fixed_off + chunk_bytes(CH) > ws_size) CH >>= 1;

  auto cl = [&](const float* s, unsigned short* d, int n) {
    castw<<<dim3((n / 4 + 255) / 256), 256, 0, stream>>>(s, d, n);
  };
  cl(Wq,  wcat0,              512 * 512);
  cl(Wkm, wcat0 + 512 * 512,  512 * 512);
  cl(Wvm, wcat0 + 1024 * 512, 512 * 512);
  cl(Wkt, wcat2,              512 * 256);
  cl(Wvt, wcat2 + 512 * 256,  512 * 256);
  cl(out_W, wout_bf, 512 * 512);
  prep_w<<<dim3(512), 256, 0, stream>>>(Wkr, rn1_g, rn1_b, bkr, Wvr, rn2_g, rn2_b, bvr,
                                        wcat1, wcat1 + 512 * 512, G1, B1, G2, B2);
  text_T<<<dim3(kB * kR, 8), 256, 0, stream>>>(re_text, rn1_g, Wkr, Tbuf);

  rowmask_kernel<<<dim3(kB * 4), 256, 0, stream>>>(cond, src_mask, re_mask,
      kaT_full, kaR_full, kaM_full, vmT_full, vmR_full, vmM_full, kB);
  silu_emb<<<dim3(kB * 2048 / 1024), 256, 0, stream>>>(emb, semb_f);
  emb_gemv2<<<dim3(256, 8), 256, 0, stream>>>(semb_f, emb_W, part_emb);
  emb_fin<<<dim3(128), 256, 0, stream>>>(part_emb, emb_b, ssb_full);

  for (int b0 = 0; b0 < kB; b0 += CH) {
    off = fixed_off;
    const int MRc = CH * 1024;
    const int MTc = CH * kNT;

    size_t xnr = pad((size_t)MRc * 512 * 2);
    if (att_bytes(CH) > xnr) xnr = att_bytes(CH);
    char* xnR = ab(xnr);
    unsigned short* xn_bf  = (unsigned short*)xnR;
    unsigned short* attT = (unsigned short*)xnR;
    float* attp = (float*)(xnR + pad((size_t)CH * 8 * 4096 * 2));
    float* part_cs = (float*)(xnR + pad((size_t)CH * 8 * 4096 * 2)
                                  + pad((size_t)CH * 8 * (size_t)kNS2 * 4096 * 4));
    unsigned short* h_bf = xn_bf;

    unsigned short* xfn_bf = (unsigned short*)ab((size_t)MTc * 256 * 2);
    unsigned short* mot_bf = (unsigned short*)ab((size_t)MRc * 512 * 2);
    float* s1k = (float*)ab((size_t)CH * 1024 * 4);
    float* s2k = (float*)ab((size_t)CH * 1024 * 4);
    float* s1v = (float*)ab((size_t)CH * 1024 * 4);
    float* s2v = (float*)ab((size_t)CH * 1024 * 4);
    unsigned short* qb_bf  = (unsigned short*)ab((size_t)MRc * 512 * 2);
    unsigned short* kc_bf  = (unsigned short*)ab((size_t)CH * 512 * kNtot * 2);
    unsigned short* vb_bf  = (unsigned short*)ab((size_t)CH * 512 * kNtot * 2);
    unsigned short* yb16 = mot_bf;

    const float* x_c   = x + (size_t)b0 * kT * 512;
    const float* xf_c  = xf + (size_t)b0 * kNT * 256;
    const float* rm_c  = re_motion + (size_t)b0 * kRL * 512;
    const float* rt_c  = re_text + (size_t)b0 * kR * 512;
    float* out_c = out + (size_t)b0 * kT * 512;

    // --- preprocessing ---
    ln_bf16<512><<<dim3(MRc), 256, 0, stream>>>(x_c, norm_g, norm_b, xn_bf);
    ln_bf16<256><<<dim3(MTc), 256, 0, stream>>>(xf_c, tnorm_g, tnorm_b, xfn_bf);
    rfk_stats<<<dim3(MRc), 256, 0, stream>>>(rm_c, rt_c, mot_bf, s1k, s2k, s1v, s2v);
    zpad_kernel<<<dim3(CH * 48), 256, 0, stream>>>(kc_bf, vb_bf, CH * 512);

    // --- fused projections (shared A, XCD-swizzled 1D grids, 3-buffer pipelined) ---
    gemm_fused<0, 12><<<dim3(12 * CH * 8), 256, 0, stream>>>(
        xn_bf, wcat0, MRc, 512, kT, kNT + kRL,
        qb_bf, kc_bf, vb_bf, bq, bkm, bvm,
        kaM_full + (size_t)b0 * kT, vmM_full + (size_t)b0 * kT,
        nullptr, nullptr, nullptr, nullptr, nullptr, nullptr, nullptr);
    gemm_fused<1, 8><<<dim3(8 * CH * 8), 256, 0, stream>>>(
        mot_bf, wcat1, MRc, 512, kRL, kNT,
        nullptr, kc_bf, vb_bf, B1, B2, nullptr,
        kaR_full + (size_t)b0 * kRL, vmR_full + (size_t)b0 * kRL,
        s1k, s2k, s1v, s2v, G1, G2, Tbuf + (size_t)b0 * kR * 512);
    gemm_fused<2, 8><<<dim3(8 * ((MTc + 127) / 128)), 256, 0, stream>>>(
        xfn_bf, wcat2, MTc, 256, kNT, 0,
        nullptr, kc_bf, vb_bf, bkt, bvt, nullptr,
        kaT_full + (size_t)b0 * kNT, vmT_full + (size_t)b0 * kNT,
        nullptr, nullptr, nullptr, nullptr, nullptr, nullptr, nullptr);

    // --- attention ---
    attp_kernel<<<dim3(CH * 8, kNS2), 256, 0, stream>>>(kc_bf, vb_bf, attp, part_cs);
    attc_kernel<<<dim3(CH * 8), 256, 0, stream>>>(attp, part_cs, attT);
    y_mfma<<<dim3(CH * 8, 8), 256, 0, stream>>>(qb_bf, attT, yb16);

    // --- modulation + output projection with fused residual ---
    mod_kernel<<<dim3(MRc), 256, 0, stream>>>(yb16, ssb_full + (size_t)b0 * 1024,
                                              snorm_g, snorm_b, h_bf);
    gemm_mfma<<<dim3(4 * CH * 8), 256, 0, stream>>>(h_bf, wout_bf, out_b,
                                                    x_c, out_c, MRc, 512);
  }
}